// Round 7
// baseline (2651.937 us; speedup 1.0000x reference)
//
#include <hip/hip_runtime.h>
#include <hip/hip_bf16.h>

constexpr int HDIM = 8;
constexpr int EDIM = 8;

// h = x @ node_W + node_b, fused with layer-0 BN stats (8-slot) and deg zeroing.
__global__ __launch_bounds__(256) void init_h_stats_kernel(
    const float* __restrict__ x, const float* __restrict__ W, const float* __restrict__ b,
    float* __restrict__ h, float* __restrict__ sums, int* __restrict__ deg, int n) {
  __shared__ float reds[256], redq[256];
  int tid = threadIdx.x, lane = tid & 63;
  int gtid = blockIdx.x * 256 + tid;
  for (int i = gtid; i < n; i += 512 * 256) deg[i] = 0;
  float wc[HDIM];
#pragma unroll
  for (int k = 0; k < HDIM; ++k) wc[k] = W[k * 64 + lane];
  float bc = b[lane];
  float s = 0.f, q = 0.f;
  int total = n * 64;
  for (int gid = gtid; gid < total; gid += 512 * 256) {
    int row = gid >> 6;
    const float* xr = x + (size_t)row * HDIM;
    float acc = bc;
#pragma unroll
    for (int k = 0; k < HDIM; ++k) acc = fmaf(xr[k], wc[k], acc);
    h[gid] = acc;
    s += acc;
    q = fmaf(acc, acc, q);
  }
  reds[tid] = s; redq[tid] = q;
  __syncthreads();
  if (tid < 64) {
    float S = reds[tid] + reds[64 + tid] + reds[128 + tid] + reds[192 + tid];
    float Q = redq[tid] + redq[64 + tid] + redq[128 + tid] + redq[192 + tid];
    int slot = blockIdx.x & 7;
    atomicAdd(&sums[slot * 128 + tid], S);
    atomicAdd(&sums[slot * 128 + 64 + tid], Q);
  }
}

__global__ void deg_kernel(const int* __restrict__ dst, int* __restrict__ deg, int E) {
  int e = blockIdx.x * 256 + threadIdx.x;
  if (e < E) atomicAdd(&deg[dst[e]], 1);
}

__global__ void scan_kernel(const int* __restrict__ deg, int* __restrict__ rowstart,
                            int* __restrict__ fillptr, int n, int total) {
  __shared__ int part[1024];
  int tid = threadIdx.x;
  int chunk = (n + 1023) >> 10;
  int lo = tid * chunk, hi = min(n, lo + chunk);
  int s = 0;
  for (int i = lo; i < hi; ++i) s += deg[i];
  part[tid] = s;
  __syncthreads();
  for (int offd = 1; offd < 1024; offd <<= 1) {
    int add = (tid >= offd) ? part[tid - offd] : 0;
    __syncthreads();
    part[tid] += add;
    __syncthreads();
  }
  int run = (tid == 0) ? 0 : part[tid - 1];
  for (int i = lo; i < hi; ++i) {
    rowstart[i] = run; fillptr[i] = run;
    run += deg[i];
  }
  if (tid == 1023) rowstart[n] = total;
}

__global__ void fill_kernel(const int* __restrict__ src, const int* __restrict__ dst,
                            const float* __restrict__ edge_attr, int* __restrict__ fillptr,
                            int* __restrict__ csr_src, float* __restrict__ ea_csr, int E) {
  int e = blockIdx.x * 256 + threadIdx.x;
  if (e >= E) return;
  int d = dst[e];
  int slot = atomicAdd(&fillptr[d], 1);
  csr_src[slot] = src[e];
  const float4* ap = (const float4*)(edge_attr + (size_t)e * EDIM);
  float4* op = (float4*)(ea_csr + (size_t)slot * EDIM);
  op[0] = ap[0];
  op[1] = ap[1];
}

// Fused BN+ReLU + message + softmax-agg. 1 wave/node, lane=channel. Edge loop x4.
__global__ __launch_bounds__(256) void aggregate_kernel(
    const float* __restrict__ h, const float* __restrict__ sums,
    const float* __restrict__ bn_g, const float* __restrict__ bn_b,
    const int* __restrict__ rowstart, const int* __restrict__ csr_src,
    const float* __restrict__ ea_csr, const float* __restrict__ edge_W,
    const float* __restrict__ edge_b, const float* __restrict__ t,
    float* __restrict__ out, int n, float invN) {
  int lane = threadIdx.x & 63;
  int node = blockIdx.x * 4 + (threadIdx.x >> 6);
  if (node >= n) return;
  float ssum = 0.f, qsum = 0.f;
#pragma unroll
  for (int k = 0; k < 8; ++k) {
    ssum += sums[k * 128 + lane];
    qsum += sums[k * 128 + 64 + lane];
  }
  float mu = ssum * invN;
  float var = qsum * invN - mu * mu;
  float aa = rsqrtf(var + 1e-5f) * bn_g[lane];
  float cc = bn_b[lane] - mu * aa;
  float wcol[EDIM];
#pragma unroll
  for (int k = 0; k < EDIM; ++k) wcol[k] = edge_W[k * 64 + lane];
  float eb = edge_b[lane];
  float tt = t[0];
  int s0 = __builtin_amdgcn_readfirstlane(rowstart[node]);
  int s1 = __builtin_amdgcn_readfirstlane(rowstart[node + 1]);
  float hd = fmaxf(fmaf(h[(size_t)node * 64 + lane], aa, cc), 0.f);
  float den = 0.f, num = 0.f;
  for (int base = s0; base < s1; base += 64) {
    int myi = base + lane;
    int srcs = (myi < s1) ? csr_src[myi] : 0;
    int cnt = min(64, s1 - base);
    int jj = 0;
    for (; jj + 4 <= cnt; jj += 4) {
      int i0 = __shfl(srcs, jj, 64);
      int i1 = __shfl(srcs, jj + 1, 64);
      int i2 = __shfl(srcs, jj + 2, 64);
      int i3 = __shfl(srcs, jj + 3, 64);
      float hv0 = h[(size_t)i0 * 64 + lane];
      float hv1 = h[(size_t)i1 * 64 + lane];
      float hv2 = h[(size_t)i2 * 64 + lane];
      float hv3 = h[(size_t)i3 * 64 + lane];
      const float4* ep = (const float4*)(ea_csr + (size_t)(base + jj) * EDIM);
      float4 a0 = ep[0], c0 = ep[1], a1 = ep[2], c1 = ep[3];
      float4 a2 = ep[4], c2 = ep[5], a3 = ep[6], c3 = ep[7];
#define EDGE_STEP(HV, A, C)                                                   \
      {                                                                        \
        float ev = eb;                                                         \
        ev = fmaf(A.x, wcol[0], ev); ev = fmaf(A.y, wcol[1], ev);              \
        ev = fmaf(A.z, wcol[2], ev); ev = fmaf(A.w, wcol[3], ev);              \
        ev = fmaf(C.x, wcol[4], ev); ev = fmaf(C.y, wcol[5], ev);              \
        ev = fmaf(C.z, wcol[6], ev); ev = fmaf(C.w, wcol[7], ev);              \
        float hn = fmaxf(fmaf(HV, aa, cc), 0.f);                               \
        float msg = fmaxf(hn + ev, 0.f) + 1e-7f;                               \
        float p = __expf(msg * tt);                                            \
        den += p;                                                              \
        num = fmaf(p, msg, num);                                               \
      }
      EDGE_STEP(hv0, a0, c0)
      EDGE_STEP(hv1, a1, c1)
      EDGE_STEP(hv2, a2, c2)
      EDGE_STEP(hv3, a3, c3)
    }
    for (; jj < cnt; ++jj) {
      int si = __shfl(srcs, jj, 64);
      float hv = h[(size_t)si * 64 + lane];
      const float4* ep = (const float4*)(ea_csr + (size_t)(base + jj) * EDIM);
      float4 a0 = ep[0], c0 = ep[1];
      EDGE_STEP(hv, a0, c0)
    }
#undef EDGE_STEP
  }
  out[(size_t)node * 64 + lane] = num / fmaxf(den, 1e-16f) + hd;
}

// Node-per-lane MLP, register-pressure-safe version:
//  - y computed in 4 chunks of 32 (8 float4 live), raw y parked in LDS
//  - LN stats in-register; phase2 normalizes z on the fly from LDS
//  - weights: wave-uniform global loads (L2 broadcast), 2-row register pipeline
//  - LDS 50.4KB -> 3 blocks/CU
__global__ __launch_bounds__(64) void mlp_lane_kernel(
    const float* __restrict__ outv, const float* __restrict__ h_in,
    const float* __restrict__ W1, const float* __restrict__ b1,
    const float* __restrict__ lng, const float* __restrict__ lnb,
    const float* __restrict__ W2, const float* __restrict__ b2,
    float* __restrict__ h_out, float* __restrict__ nextsums, int n) {
  __shared__ float xb[64 * 65];    // [c][node]: x, later out-transpose
  __shared__ float yb[64 * 132];   // [node][hh]: raw y, stride 132 (16B-aligned)
  const int l = threadIdx.x;
  const int n0 = blockIdx.x * 64;
  // coalesced x load, transposed so phase1 reads are lane-consecutive
#pragma unroll 4
  for (int r = 0; r < 64; ++r) {
    int nd = n0 + r;
    xb[l * 65 + r] = (nd < n) ? outv[(size_t)nd * 64 + l] : 0.f;
  }
  __syncthreads();
  const float4* W1v = (const float4*)W1;  // row c -> idx c*32 + hb*8 + j
  float s1 = 0.f, q1 = 0.f;
  for (int hb = 0; hb < 4; ++hb) {
    float4 y[8];
    const float4* bp = (const float4*)b1 + hb * 8;
#pragma unroll
    for (int j = 0; j < 8; ++j) y[j] = bp[j];
    float4 wA[8], wB[8];
#pragma unroll
    for (int j = 0; j < 8; ++j) wA[j] = W1v[hb * 8 + j];
#pragma unroll
    for (int j = 0; j < 8; ++j) wB[j] = W1v[32 + hb * 8 + j];
    for (int c = 0; c < 64; c += 2) {
      float x0 = xb[c * 65 + l];
#pragma unroll
      for (int j = 0; j < 8; ++j) {
        y[j].x = fmaf(x0, wA[j].x, y[j].x);
        y[j].y = fmaf(x0, wA[j].y, y[j].y);
        y[j].z = fmaf(x0, wA[j].z, y[j].z);
        y[j].w = fmaf(x0, wA[j].w, y[j].w);
      }
      if (c + 2 < 64) {
#pragma unroll
        for (int j = 0; j < 8; ++j) wA[j] = W1v[(c + 2) * 32 + hb * 8 + j];
      }
      float x1 = xb[(c + 1) * 65 + l];
#pragma unroll
      for (int j = 0; j < 8; ++j) {
        y[j].x = fmaf(x1, wB[j].x, y[j].x);
        y[j].y = fmaf(x1, wB[j].y, y[j].y);
        y[j].z = fmaf(x1, wB[j].z, y[j].z);
        y[j].w = fmaf(x1, wB[j].w, y[j].w);
      }
      if (c + 3 < 64) {
#pragma unroll
        for (int j = 0; j < 8; ++j) wB[j] = W1v[(c + 3) * 32 + hb * 8 + j];
      }
    }
#pragma unroll
    for (int j = 0; j < 8; ++j) {
      *(float4*)&yb[l * 132 + hb * 32 + 4 * j] = y[j];
      s1 += (y[j].x + y[j].y) + (y[j].z + y[j].w);
      q1 = fmaf(y[j].x, y[j].x, q1); q1 = fmaf(y[j].y, y[j].y, q1);
      q1 = fmaf(y[j].z, y[j].z, q1); q1 = fmaf(y[j].w, y[j].w, q1);
    }
  }
  float mu = s1 * (1.f / 128.f);
  float var = q1 * (1.f / 128.f) - mu * mu;
  float rstd = rsqrtf(var + 1e-5f);
  __syncthreads();  // all lanes done with xb x-values; xb becomes out buffer
  const float4* W2v = (const float4*)W2;  // row hh -> idx hh*16 + ob*4 + j
  const float4* lgv = (const float4*)lng;
  const float4* lbv = (const float4*)lnb;
  for (int ob = 0; ob < 4; ++ob) {  // 16 output channels per pass
    float4 oacc[4];
    const float4* bp2 = (const float4*)b2 + ob * 4;
#pragma unroll
    for (int j = 0; j < 4; ++j) oacc[j] = bp2[j];
    float4 wA[16], wB[16];
#pragma unroll
    for (int j = 0; j < 16; ++j) wA[j] = W2v[(j >> 2) * 16 + ob * 4 + (j & 3)];
#pragma unroll
    for (int j = 0; j < 16; ++j) wB[j] = W2v[(4 + (j >> 2)) * 16 + ob * 4 + (j & 3)];
    for (int h4 = 0; h4 < 32; ++h4) {  // 4 hidden per iter
      float4 yq = *(const float4*)&yb[l * 132 + 4 * h4];
      float4 g = lgv[h4], bb = lbv[h4];
      float z0 = fmaxf((yq.x - mu) * rstd * g.x + bb.x, 0.f);
      float z1 = fmaxf((yq.y - mu) * rstd * g.y + bb.y, 0.f);
      float z2 = fmaxf((yq.z - mu) * rstd * g.z + bb.z, 0.f);
      float z3 = fmaxf((yq.w - mu) * rstd * g.w + bb.w, 0.f);
      const float4* w = (h4 & 1) ? wB : wA;
#pragma unroll
      for (int j = 0; j < 4; ++j) {
        oacc[j].x = fmaf(z0, w[0 * 4 + j].x, oacc[j].x);
        oacc[j].y = fmaf(z0, w[0 * 4 + j].y, oacc[j].y);
        oacc[j].z = fmaf(z0, w[0 * 4 + j].z, oacc[j].z);
        oacc[j].w = fmaf(z0, w[0 * 4 + j].w, oacc[j].w);
        oacc[j].x = fmaf(z1, w[1 * 4 + j].x, oacc[j].x);
        oacc[j].y = fmaf(z1, w[1 * 4 + j].y, oacc[j].y);
        oacc[j].z = fmaf(z1, w[1 * 4 + j].z, oacc[j].z);
        oacc[j].w = fmaf(z1, w[1 * 4 + j].w, oacc[j].w);
        oacc[j].x = fmaf(z2, w[2 * 4 + j].x, oacc[j].x);
        oacc[j].y = fmaf(z2, w[2 * 4 + j].y, oacc[j].y);
        oacc[j].z = fmaf(z2, w[2 * 4 + j].z, oacc[j].z);
        oacc[j].w = fmaf(z2, w[2 * 4 + j].w, oacc[j].w);
        oacc[j].x = fmaf(z3, w[3 * 4 + j].x, oacc[j].x);
        oacc[j].y = fmaf(z3, w[3 * 4 + j].y, oacc[j].y);
        oacc[j].z = fmaf(z3, w[3 * 4 + j].z, oacc[j].z);
        oacc[j].w = fmaf(z3, w[3 * 4 + j].w, oacc[j].w);
      }
      // prefetch rows for h4+2 into the buffer just consumed
      if (h4 + 2 < 32) {
        float4* wp = (h4 & 1) ? wB : wA;
#pragma unroll
        for (int j = 0; j < 16; ++j)
          wp[j] = W2v[((h4 + 2) * 4 + (j >> 2)) * 16 + ob * 4 + (j & 3)];
      }
    }
    // park out chunk (16 channels) transposed: xb[c][node]
#pragma unroll
    for (int j = 0; j < 4; ++j) {
      xb[(ob * 16 + 4 * j + 0) * 65 + l] = oacc[j].x;
      xb[(ob * 16 + 4 * j + 1) * 65 + l] = oacc[j].y;
      xb[(ob * 16 + 4 * j + 2) * 65 + l] = oacc[j].z;
      xb[(ob * 16 + 4 * j + 3) * 65 + l] = oacc[j].w;
    }
  }
  __syncthreads();
  // residual + coalesced store + next-layer BN partial stats (lane = channel)
  float s = 0.f, q = 0.f;
#pragma unroll 4
  for (int r = 0; r < 64; ++r) {
    int nd = n0 + r;
    if (nd < n) {
      float v = h_in[(size_t)nd * 64 + l] + xb[l * 65 + r];
      h_out[(size_t)nd * 64 + l] = v;
      s += v;
      q = fmaf(v, v, q);
    }
  }
  if (nextsums != nullptr) {
    int slot = blockIdx.x & 7;
    atomicAdd(&nextsums[slot * 128 + l], s);
    atomicAdd(&nextsums[slot * 128 + 64 + l], q);
  }
}

extern "C" void kernel_launch(void* const* d_in, const int* in_sizes, int n_in,
                              void* d_out, int out_size, void* d_ws, size_t ws_size,
                              hipStream_t stream) {
  const float* x = (const float*)d_in[0];
  const int* edge_index = (const int*)d_in[1];
  const float* edge_attr = (const float*)d_in[2];
  const float* node_W = (const float*)d_in[3];
  const float* node_b = (const float*)d_in[4];
  const float* edge_W = (const float*)d_in[5];
  const float* edge_b = (const float*)d_in[6];
  const float* bn_g = (const float*)d_in[7];
  const float* bn_b = (const float*)d_in[8];
  const float* t = (const float*)d_in[9];
  const float* W1 = (const float*)d_in[10];
  const float* b1 = (const float*)d_in[11];
  const float* ln_g = (const float*)d_in[12];
  const float* ln_b = (const float*)d_in[13];
  const float* W2 = (const float*)d_in[14];
  const float* b2 = (const float*)d_in[15];

  int N = in_sizes[0] / HDIM;
  int E = in_sizes[1] / 2;
  const int* srcp = edge_index;
  const int* dstp = edge_index + E;

  char* ws = (char*)d_ws;
  size_t off = 0;
  auto alloc = [&](size_t bytes) {
    char* p = ws + off;
    off = (off + bytes + 255) & ~(size_t)255;
    return p;
  };
  int* deg = (int*)alloc((size_t)N * 4);
  int* rowstart = (int*)alloc(((size_t)N + 1) * 4);
  int* fillptr = (int*)alloc((size_t)N * 4);
  float* bnsums = (float*)alloc(3 * 1024 * 4);  // 3 layers x 8 slots x 128
  int* csr_src = (int*)alloc((size_t)E * 4);
  float* ea_csr = (float*)alloc((size_t)E * EDIM * 4);
  float* h = (float*)alloc((size_t)N * 64 * 4);
  float* outv = (float*)alloc((size_t)N * 64 * 4);
  (void)ws_size; (void)n_in; (void)out_size;

  hipMemsetAsync(bnsums, 0, 3 * 1024 * 4, stream);
  init_h_stats_kernel<<<512, 256, 0, stream>>>(x, node_W, node_b, h, bnsums, deg, N);
  deg_kernel<<<(E + 255) / 256, 256, 0, stream>>>(dstp, deg, E);
  scan_kernel<<<1, 1024, 0, stream>>>(deg, rowstart, fillptr, N, E);
  fill_kernel<<<(E + 255) / 256, 256, 0, stream>>>(srcp, dstp, edge_attr, fillptr, csr_src, ea_csr, E);

  float invN = 1.0f / (float)N;
  int mlp_blocks = (N + 63) / 64;
  for (int l = 0; l < 3; ++l) {
    aggregate_kernel<<<(N + 3) / 4, 256, 0, stream>>>(
        h, bnsums + l * 1024, bn_g + l * 64, bn_b + l * 64, rowstart, csr_src, ea_csr,
        edge_W, edge_b, t + l, outv, N, invN);
    float* hout = (l == 2) ? (float*)d_out : h;
    float* nxt = (l == 2) ? nullptr : (bnsums + (l + 1) * 1024);
    mlp_lane_kernel<<<mlp_blocks, 64, 0, stream>>>(outv, h, W1 + (size_t)l * 8192, b1 + l * 128,
                                                   ln_g + l * 128, ln_b + l * 128,
                                                   W2 + (size_t)l * 8192, b2 + l * 64, hout, nxt, N);
  }
}

// Round 8
// 462.093 us; speedup vs baseline: 5.7390x; 5.7390x over previous
//
#include <hip/hip_runtime.h>
#include <hip/hip_bf16.h>

constexpr int HDIM = 8;
constexpr int EDIM = 8;

// h = x @ node_W + node_b, fused with layer-0 BN stats (8-slot) and deg zeroing.
__global__ __launch_bounds__(256) void init_h_stats_kernel(
    const float* __restrict__ x, const float* __restrict__ W, const float* __restrict__ b,
    float* __restrict__ h, float* __restrict__ sums, int* __restrict__ deg, int n) {
  __shared__ float reds[256], redq[256];
  int tid = threadIdx.x, lane = tid & 63;
  int gtid = blockIdx.x * 256 + tid;
  for (int i = gtid; i < n; i += 512 * 256) deg[i] = 0;
  float wc[HDIM];
#pragma unroll
  for (int k = 0; k < HDIM; ++k) wc[k] = W[k * 64 + lane];
  float bc = b[lane];
  float s = 0.f, q = 0.f;
  int total = n * 64;
  for (int gid = gtid; gid < total; gid += 512 * 256) {
    int row = gid >> 6;
    const float* xr = x + (size_t)row * HDIM;
    float acc = bc;
#pragma unroll
    for (int k = 0; k < HDIM; ++k) acc = fmaf(xr[k], wc[k], acc);
    h[gid] = acc;
    s += acc;
    q = fmaf(acc, acc, q);
  }
  reds[tid] = s; redq[tid] = q;
  __syncthreads();
  if (tid < 64) {
    float S = reds[tid] + reds[64 + tid] + reds[128 + tid] + reds[192 + tid];
    float Q = redq[tid] + redq[64 + tid] + redq[128 + tid] + redq[192 + tid];
    int slot = blockIdx.x & 7;
    atomicAdd(&sums[slot * 128 + tid], S);
    atomicAdd(&sums[slot * 128 + 64 + tid], Q);
  }
}

__global__ void deg_kernel(const int* __restrict__ dst, int* __restrict__ deg, int E) {
  int e = blockIdx.x * 256 + threadIdx.x;
  if (e < E) atomicAdd(&deg[dst[e]], 1);
}

__global__ void scan_kernel(const int* __restrict__ deg, int* __restrict__ rowstart,
                            int* __restrict__ fillptr, int n, int total) {
  __shared__ int part[1024];
  int tid = threadIdx.x;
  int chunk = (n + 1023) >> 10;
  int lo = tid * chunk, hi = min(n, lo + chunk);
  int s = 0;
  for (int i = lo; i < hi; ++i) s += deg[i];
  part[tid] = s;
  __syncthreads();
  for (int offd = 1; offd < 1024; offd <<= 1) {
    int add = (tid >= offd) ? part[tid - offd] : 0;
    __syncthreads();
    part[tid] += add;
    __syncthreads();
  }
  int run = (tid == 0) ? 0 : part[tid - 1];
  for (int i = lo; i < hi; ++i) {
    rowstart[i] = run; fillptr[i] = run;
    run += deg[i];
  }
  if (tid == 1023) rowstart[n] = total;
}

__global__ void fill_kernel(const int* __restrict__ src, const int* __restrict__ dst,
                            const float* __restrict__ edge_attr, int* __restrict__ fillptr,
                            int* __restrict__ csr_src, float* __restrict__ ea_csr, int E) {
  int e = blockIdx.x * 256 + threadIdx.x;
  if (e >= E) return;
  int d = dst[e];
  int slot = atomicAdd(&fillptr[d], 1);
  csr_src[slot] = src[e];
  const float4* ap = (const float4*)(edge_attr + (size_t)e * EDIM);
  float4* op = (float4*)(ea_csr + (size_t)slot * EDIM);
  op[0] = ap[0];
  op[1] = ap[1];
}

// Fused BN+ReLU + message + softmax-agg. 1 wave/node, lane=channel. Edge loop x4.
__global__ __launch_bounds__(256) void aggregate_kernel(
    const float* __restrict__ h, const float* __restrict__ sums,
    const float* __restrict__ bn_g, const float* __restrict__ bn_b,
    const int* __restrict__ rowstart, const int* __restrict__ csr_src,
    const float* __restrict__ ea_csr, const float* __restrict__ edge_W,
    const float* __restrict__ edge_b, const float* __restrict__ t,
    float* __restrict__ out, int n, float invN) {
  int lane = threadIdx.x & 63;
  int node = blockIdx.x * 4 + (threadIdx.x >> 6);
  if (node >= n) return;
  float ssum = 0.f, qsum = 0.f;
#pragma unroll
  for (int k = 0; k < 8; ++k) {
    ssum += sums[k * 128 + lane];
    qsum += sums[k * 128 + 64 + lane];
  }
  float mu = ssum * invN;
  float var = qsum * invN - mu * mu;
  float aa = rsqrtf(var + 1e-5f) * bn_g[lane];
  float cc = bn_b[lane] - mu * aa;
  float wcol[EDIM];
#pragma unroll
  for (int k = 0; k < EDIM; ++k) wcol[k] = edge_W[k * 64 + lane];
  float eb = edge_b[lane];
  float tt = t[0];
  int s0 = __builtin_amdgcn_readfirstlane(rowstart[node]);
  int s1 = __builtin_amdgcn_readfirstlane(rowstart[node + 1]);
  float hd = fmaxf(fmaf(h[(size_t)node * 64 + lane], aa, cc), 0.f);
  float den = 0.f, num = 0.f;
  for (int base = s0; base < s1; base += 64) {
    int myi = base + lane;
    int srcs = (myi < s1) ? csr_src[myi] : 0;
    int cnt = min(64, s1 - base);
    int jj = 0;
    for (; jj + 4 <= cnt; jj += 4) {
      int i0 = __shfl(srcs, jj, 64);
      int i1 = __shfl(srcs, jj + 1, 64);
      int i2 = __shfl(srcs, jj + 2, 64);
      int i3 = __shfl(srcs, jj + 3, 64);
      float hv0 = h[(size_t)i0 * 64 + lane];
      float hv1 = h[(size_t)i1 * 64 + lane];
      float hv2 = h[(size_t)i2 * 64 + lane];
      float hv3 = h[(size_t)i3 * 64 + lane];
      const float4* ep = (const float4*)(ea_csr + (size_t)(base + jj) * EDIM);
      float4 a0 = ep[0], c0 = ep[1], a1 = ep[2], c1 = ep[3];
      float4 a2 = ep[4], c2 = ep[5], a3 = ep[6], c3 = ep[7];
#define EDGE_STEP(HV, A, C)                                                   \
      {                                                                        \
        float ev = eb;                                                         \
        ev = fmaf(A.x, wcol[0], ev); ev = fmaf(A.y, wcol[1], ev);              \
        ev = fmaf(A.z, wcol[2], ev); ev = fmaf(A.w, wcol[3], ev);              \
        ev = fmaf(C.x, wcol[4], ev); ev = fmaf(C.y, wcol[5], ev);              \
        ev = fmaf(C.z, wcol[6], ev); ev = fmaf(C.w, wcol[7], ev);              \
        float hn = fmaxf(fmaf(HV, aa, cc), 0.f);                               \
        float msg = fmaxf(hn + ev, 0.f) + 1e-7f;                               \
        float p = __expf(msg * tt);                                            \
        den += p;                                                              \
        num = fmaf(p, msg, num);                                               \
      }
      EDGE_STEP(hv0, a0, c0)
      EDGE_STEP(hv1, a1, c1)
      EDGE_STEP(hv2, a2, c2)
      EDGE_STEP(hv3, a3, c3)
    }
    for (; jj < cnt; ++jj) {
      int si = __shfl(srcs, jj, 64);
      float hv = h[(size_t)si * 64 + lane];
      const float4* ep = (const float4*)(ea_csr + (size_t)(base + jj) * EDIM);
      float4 a0 = ep[0], c0 = ep[1];
      EDGE_STEP(hv, a0, c0)
    }
#undef EDGE_STEP
  }
  out[(size_t)node * 64 + lane] = num / fmaxf(den, 1e-16f) + hd;
}

// Tiled-GEMM MLP: 256 threads (4 waves), 64 nodes/block. Thread tile 4x8 (phase1)
// and 4x4 (phase2); LDS: xT/zT (stride 68) + weights; 68KB -> 2 blocks/CU = 8 waves.
__global__ __launch_bounds__(256) void mlp_tile_kernel(
    const float* __restrict__ outv, const float* __restrict__ h_in,
    const float* __restrict__ W1, const float* __restrict__ b1,
    const float* __restrict__ lng, const float* __restrict__ lnb,
    const float* __restrict__ W2, const float* __restrict__ b2,
    float* __restrict__ h_out, float* __restrict__ nextsums, int n) {
  __shared__ float bufA[128 * 68];  // xT[64][68] -> red zone -> zT[128][68]
  __shared__ float bufB[64 * 128];  // W1s then W2s
  __shared__ float mstat[128];      // mu[64], rstd[64]
  const int tid = threadIdx.x;
  const int tx = tid & 15, ty = tid >> 4;
  const int n0 = blockIdx.x * 64;
  // stage xT (transposed) + W1
#pragma unroll
  for (int i = 0; i < 16; ++i) {
    int gid = i * 256 + tid;
    int node = gid >> 6, c = gid & 63;
    int nd = n0 + node;
    bufA[c * 68 + node] = (nd < n) ? outv[(size_t)nd * 64 + c] : 0.f;
  }
  {
    const float4* w1g = (const float4*)W1;
    float4* w1s = (float4*)bufB;
#pragma unroll
    for (int i = 0; i < 8; ++i) w1s[i * 256 + tid] = w1g[i * 256 + tid];
  }
  __syncthreads();
  // ---- phase 1: y[4 nodes][8 ch] = x @ W1 + b1 ----
  const float4* b1v = (const float4*)b1;
  float4 acc0[4], acc1[4];
  {
    float4 bA = b1v[2 * ty], bB = b1v[2 * ty + 1];
#pragma unroll
    for (int i = 0; i < 4; ++i) { acc0[i] = bA; acc1[i] = bB; }
  }
  for (int k = 0; k < 64; ++k) {
    float4 xv = *(const float4*)&bufA[k * 68 + 4 * tx];
    float4 w0 = *(const float4*)&bufB[k * 128 + 8 * ty];
    float4 w1 = *(const float4*)&bufB[k * 128 + 8 * ty + 4];
#define FMA8(I, XS)                                                            \
    acc0[I].x = fmaf(XS, w0.x, acc0[I].x);                                     \
    acc0[I].y = fmaf(XS, w0.y, acc0[I].y);                                     \
    acc0[I].z = fmaf(XS, w0.z, acc0[I].z);                                     \
    acc0[I].w = fmaf(XS, w0.w, acc0[I].w);                                     \
    acc1[I].x = fmaf(XS, w1.x, acc1[I].x);                                     \
    acc1[I].y = fmaf(XS, w1.y, acc1[I].y);                                     \
    acc1[I].z = fmaf(XS, w1.z, acc1[I].z);                                     \
    acc1[I].w = fmaf(XS, w1.w, acc1[I].w);
    FMA8(0, xv.x) FMA8(1, xv.y) FMA8(2, xv.z) FMA8(3, xv.w)
#undef FMA8
  }
  // LN partials per (node, ty): safe region (rows 64+), no sync needed pre-store
  float* redS = bufA + 64 * 68;
  float* redQ = redS + 16 * 68;
#pragma unroll
  for (int i = 0; i < 4; ++i) {
    float si = ((acc0[i].x + acc0[i].y) + (acc0[i].z + acc0[i].w)) +
               ((acc1[i].x + acc1[i].y) + (acc1[i].z + acc1[i].w));
    float qi = 0.f;
    qi = fmaf(acc0[i].x, acc0[i].x, qi); qi = fmaf(acc0[i].y, acc0[i].y, qi);
    qi = fmaf(acc0[i].z, acc0[i].z, qi); qi = fmaf(acc0[i].w, acc0[i].w, qi);
    qi = fmaf(acc1[i].x, acc1[i].x, qi); qi = fmaf(acc1[i].y, acc1[i].y, qi);
    qi = fmaf(acc1[i].z, acc1[i].z, qi); qi = fmaf(acc1[i].w, acc1[i].w, qi);
    redS[ty * 68 + 4 * tx + i] = si;
    redQ[ty * 68 + 4 * tx + i] = qi;
  }
  __syncthreads();  // phase1 LDS reads + red stores complete
  // stage W2 (bufB free) while 64 threads compute mu/rstd
  {
    const float4* w2g = (const float4*)W2;
    float4* w2s = (float4*)bufB;
#pragma unroll
    for (int i = 0; i < 8; ++i) w2s[i * 256 + tid] = w2g[i * 256 + tid];
  }
  if (tid < 64) {
    float S = 0.f, Q = 0.f;
#pragma unroll
    for (int t = 0; t < 16; ++t) { S += redS[t * 68 + tid]; Q += redQ[t * 68 + tid]; }
    float mu = S * (1.f / 128.f);
    float var = Q * (1.f / 128.f) - mu * mu;
    mstat[tid] = mu;
    mstat[64 + tid] = rsqrtf(var + 1e-5f);
  }
  __syncthreads();
  // z = relu(LN(y)) written transposed into bufA rows 0..127
  {
    const float4* lgv = (const float4*)lng;
    const float4* lbv = (const float4*)lnb;
    float4 g0 = lgv[2 * ty], g1 = lgv[2 * ty + 1];
    float4 e0 = lbv[2 * ty], e1 = lbv[2 * ty + 1];
    float mu0 = mstat[4 * tx + 0], mu1 = mstat[4 * tx + 1];
    float mu2 = mstat[4 * tx + 2], mu3 = mstat[4 * tx + 3];
    float r0 = mstat[64 + 4 * tx + 0], r1 = mstat[64 + 4 * tx + 1];
    float r2 = mstat[64 + 4 * tx + 2], r3 = mstat[64 + 4 * tx + 3];
#define ZROW(ROW, A, C, G, E)                                                  \
    { float4 zr;                                                               \
      zr.x = fmaxf((A[0].C - mu0) * r0 * (G).C + (E).C, 0.f);                  \
      zr.y = fmaxf((A[1].C - mu1) * r1 * (G).C + (E).C, 0.f);                  \
      zr.z = fmaxf((A[2].C - mu2) * r2 * (G).C + (E).C, 0.f);                  \
      zr.w = fmaxf((A[3].C - mu3) * r3 * (G).C + (E).C, 0.f);                  \
      *(float4*)&bufA[(8 * ty + (ROW)) * 68 + 4 * tx] = zr; }
    ZROW(0, acc0, x, g0, e0)
    ZROW(1, acc0, y, g0, e0)
    ZROW(2, acc0, z, g0, e0)
    ZROW(3, acc0, w, g0, e0)
    ZROW(4, acc1, x, g1, e1)
    ZROW(5, acc1, y, g1, e1)
    ZROW(6, acc1, z, g1, e1)
    ZROW(7, acc1, w, g1, e1)
#undef ZROW
  }
  __syncthreads();
  // ---- phase 2: out[4 nodes][4 ch] = z @ W2 + b2 ----
  float4 oa[4];
  {
    float4 bc = ((const float4*)b2)[ty];
#pragma unroll
    for (int i = 0; i < 4; ++i) oa[i] = bc;
  }
  for (int k = 0; k < 128; ++k) {
    float4 zv = *(const float4*)&bufA[k * 68 + 4 * tx];
    float4 wv = *(const float4*)&bufB[k * 64 + 4 * ty];
#define P2(I, ZS)                                                              \
    oa[I].x = fmaf(ZS, wv.x, oa[I].x);                                         \
    oa[I].y = fmaf(ZS, wv.y, oa[I].y);                                         \
    oa[I].z = fmaf(ZS, wv.z, oa[I].z);                                         \
    oa[I].w = fmaf(ZS, wv.w, oa[I].w);
    P2(0, zv.x) P2(1, zv.y) P2(2, zv.z) P2(3, zv.w)
#undef P2
  }
  // residual + store + per-channel partials
  float4 ps = make_float4(0.f, 0.f, 0.f, 0.f);
  float4 pq = make_float4(0.f, 0.f, 0.f, 0.f);
#pragma unroll
  for (int i = 0; i < 4; ++i) {
    int nd = n0 + 4 * tx + i;
    if (nd < n) {
      float4 hv = *(const float4*)&h_in[(size_t)nd * 64 + 4 * ty];
      float4 v;
      v.x = hv.x + oa[i].x; v.y = hv.y + oa[i].y;
      v.z = hv.z + oa[i].z; v.w = hv.w + oa[i].w;
      *(float4*)&h_out[(size_t)nd * 64 + 4 * ty] = v;
      ps.x += v.x; ps.y += v.y; ps.z += v.z; ps.w += v.w;
      pq.x = fmaf(v.x, v.x, pq.x); pq.y = fmaf(v.y, v.y, pq.y);
      pq.z = fmaf(v.z, v.z, pq.z); pq.w = fmaf(v.w, v.w, pq.w);
    }
  }
  if (nextsums != nullptr) {
    __syncthreads();  // phase2 zT reads done; bufA free
    float* rs = bufA;             // [64 ch][17]
    float* rq = bufA + 64 * 17;
    rs[(4 * ty + 0) * 17 + tx] = ps.x;
    rs[(4 * ty + 1) * 17 + tx] = ps.y;
    rs[(4 * ty + 2) * 17 + tx] = ps.z;
    rs[(4 * ty + 3) * 17 + tx] = ps.w;
    rq[(4 * ty + 0) * 17 + tx] = pq.x;
    rq[(4 * ty + 1) * 17 + tx] = pq.y;
    rq[(4 * ty + 2) * 17 + tx] = pq.z;
    rq[(4 * ty + 3) * 17 + tx] = pq.w;
    __syncthreads();
    if (tid < 64) {
      float S = 0.f, Q = 0.f;
#pragma unroll
      for (int t = 0; t < 16; ++t) { S += rs[tid * 17 + t]; Q += rq[tid * 17 + t]; }
      int slot = blockIdx.x & 7;
      atomicAdd(&nextsums[slot * 128 + tid], S);
      atomicAdd(&nextsums[slot * 128 + 64 + tid], Q);
    }
  }
}

extern "C" void kernel_launch(void* const* d_in, const int* in_sizes, int n_in,
                              void* d_out, int out_size, void* d_ws, size_t ws_size,
                              hipStream_t stream) {
  const float* x = (const float*)d_in[0];
  const int* edge_index = (const int*)d_in[1];
  const float* edge_attr = (const float*)d_in[2];
  const float* node_W = (const float*)d_in[3];
  const float* node_b = (const float*)d_in[4];
  const float* edge_W = (const float*)d_in[5];
  const float* edge_b = (const float*)d_in[6];
  const float* bn_g = (const float*)d_in[7];
  const float* bn_b = (const float*)d_in[8];
  const float* t = (const float*)d_in[9];
  const float* W1 = (const float*)d_in[10];
  const float* b1 = (const float*)d_in[11];
  const float* ln_g = (const float*)d_in[12];
  const float* ln_b = (const float*)d_in[13];
  const float* W2 = (const float*)d_in[14];
  const float* b2 = (const float*)d_in[15];

  int N = in_sizes[0] / HDIM;
  int E = in_sizes[1] / 2;
  const int* srcp = edge_index;
  const int* dstp = edge_index + E;

  char* ws = (char*)d_ws;
  size_t off = 0;
  auto alloc = [&](size_t bytes) {
    char* p = ws + off;
    off = (off + bytes + 255) & ~(size_t)255;
    return p;
  };
  int* deg = (int*)alloc((size_t)N * 4);
  int* rowstart = (int*)alloc(((size_t)N + 1) * 4);
  int* fillptr = (int*)alloc((size_t)N * 4);
  float* bnsums = (float*)alloc(3 * 1024 * 4);  // 3 layers x 8 slots x 128
  int* csr_src = (int*)alloc((size_t)E * 4);
  float* ea_csr = (float*)alloc((size_t)E * EDIM * 4);
  float* h = (float*)alloc((size_t)N * 64 * 4);
  float* outv = (float*)alloc((size_t)N * 64 * 4);
  (void)ws_size; (void)n_in; (void)out_size;

  hipMemsetAsync(bnsums, 0, 3 * 1024 * 4, stream);
  init_h_stats_kernel<<<512, 256, 0, stream>>>(x, node_W, node_b, h, bnsums, deg, N);
  deg_kernel<<<(E + 255) / 256, 256, 0, stream>>>(dstp, deg, E);
  scan_kernel<<<1, 1024, 0, stream>>>(deg, rowstart, fillptr, N, E);
  fill_kernel<<<(E + 255) / 256, 256, 0, stream>>>(srcp, dstp, edge_attr, fillptr, csr_src, ea_csr, E);

  float invN = 1.0f / (float)N;
  int mlp_blocks = (N + 63) / 64;
  for (int l = 0; l < 3; ++l) {
    aggregate_kernel<<<(N + 3) / 4, 256, 0, stream>>>(
        h, bnsums + l * 1024, bn_g + l * 64, bn_b + l * 64, rowstart, csr_src, ea_csr,
        edge_W, edge_b, t + l, outv, N, invN);
    float* hout = (l == 2) ? (float*)d_out : h;
    float* nxt = (l == 2) ? nullptr : (bnsums + (l + 1) * 1024);
    mlp_tile_kernel<<<mlp_blocks, 256, 0, stream>>>(outv, h, W1 + (size_t)l * 8192, b1 + l * 128,
                                                    ln_g + l * 128, ln_b + l * 128,
                                                    W2 + (size_t)l * 8192, b2 + l * 64, hout, nxt, N);
  }
}

// Round 9
// 361.471 us; speedup vs baseline: 7.3365x; 1.2784x over previous
//
#include <hip/hip_runtime.h>
#include <hip/hip_bf16.h>

constexpr int HDIM = 8;
constexpr int EDIM = 8;

// h = x @ node_W + node_b, fused with layer-0 BN stats (8-slot) and deg zeroing.
__global__ __launch_bounds__(256) void init_h_stats_kernel(
    const float* __restrict__ x, const float* __restrict__ W, const float* __restrict__ b,
    float* __restrict__ h, float* __restrict__ sums, int* __restrict__ deg, int n) {
  __shared__ float reds[256], redq[256];
  int tid = threadIdx.x, lane = tid & 63;
  int gtid = blockIdx.x * 256 + tid;
  for (int i = gtid; i < n; i += 512 * 256) deg[i] = 0;
  float wc[HDIM];
#pragma unroll
  for (int k = 0; k < HDIM; ++k) wc[k] = W[k * 64 + lane];
  float bc = b[lane];
  float s = 0.f, q = 0.f;
  int total = n * 64;
  for (int gid = gtid; gid < total; gid += 512 * 256) {
    int row = gid >> 6;
    const float* xr = x + (size_t)row * HDIM;
    float acc = bc;
#pragma unroll
    for (int k = 0; k < HDIM; ++k) acc = fmaf(xr[k], wc[k], acc);
    h[gid] = acc;
    s += acc;
    q = fmaf(acc, acc, q);
  }
  reds[tid] = s; redq[tid] = q;
  __syncthreads();
  if (tid < 64) {
    float S = reds[tid] + reds[64 + tid] + reds[128 + tid] + reds[192 + tid];
    float Q = redq[tid] + redq[64 + tid] + redq[128 + tid] + redq[192 + tid];
    int slot = blockIdx.x & 7;
    atomicAdd(&sums[slot * 128 + tid], S);
    atomicAdd(&sums[slot * 128 + 64 + tid], Q);
  }
}

__global__ void deg_kernel(const int* __restrict__ dst, int* __restrict__ deg, int E) {
  int e = blockIdx.x * 256 + threadIdx.x;
  if (e < E) atomicAdd(&deg[dst[e]], 1);
}

// 3-dispatch device-wide exclusive scan (replaces the 110us single-block scan)
__global__ __launch_bounds__(256) void scan_part_kernel(const int* __restrict__ deg,
                                                        int* __restrict__ partials, int n) {
  __shared__ int sh[256];
  int tid = threadIdx.x, idx = blockIdx.x * 256 + tid;
  int v = (idx < n) ? deg[idx] : 0;
  sh[tid] = v;
  __syncthreads();
  for (int o = 128; o > 0; o >>= 1) {
    if (tid < o) sh[tid] += sh[tid + o];
    __syncthreads();
  }
  if (tid == 0) partials[blockIdx.x] = sh[0];
}

__global__ __launch_bounds__(1024) void scan_top_kernel(int* __restrict__ partials, int nb) {
  __shared__ int sh[1024];
  int tid = threadIdx.x;
  int v = (tid < nb) ? partials[tid] : 0;
  sh[tid] = v;
  __syncthreads();
  for (int o = 1; o < 1024; o <<= 1) {
    int a = (tid >= o) ? sh[tid - o] : 0;
    __syncthreads();
    sh[tid] += a;
    __syncthreads();
  }
  if (tid < nb) partials[tid] = sh[tid] - v;  // exclusive
}

__global__ __launch_bounds__(256) void scan_fill_kernel(
    const int* __restrict__ deg, const int* __restrict__ partials,
    int* __restrict__ rowstart, int* __restrict__ fillptr, int n, int total) {
  __shared__ int sh[256];
  int tid = threadIdx.x, idx = blockIdx.x * 256 + tid;
  int v = (idx < n) ? deg[idx] : 0;
  sh[tid] = v;
  __syncthreads();
  for (int o = 1; o < 256; o <<= 1) {
    int a = (tid >= o) ? sh[tid - o] : 0;
    __syncthreads();
    sh[tid] += a;
    __syncthreads();
  }
  if (idx < n) {
    int rs = partials[blockIdx.x] + sh[tid] - v;
    rowstart[idx] = rs;
    fillptr[idx] = rs;
  }
  if (blockIdx.x == 0 && tid == 0) rowstart[n] = total;
}

__global__ void fill_kernel(const int* __restrict__ src, const int* __restrict__ dst,
                            const float* __restrict__ edge_attr, int* __restrict__ fillptr,
                            int* __restrict__ csr_src, float* __restrict__ ea_csr, int E) {
  int e = blockIdx.x * 256 + threadIdx.x;
  if (e >= E) return;
  int d = dst[e];
  int slot = atomicAdd(&fillptr[d], 1);
  csr_src[slot] = src[e];
  const float4* ap = (const float4*)(edge_attr + (size_t)e * EDIM);
  float4* op = (float4*)(ea_csr + (size_t)slot * EDIM);
  op[0] = ap[0];
  op[1] = ap[1];
}

// Fused BN+ReLU + message + softmax-agg. 1 wave/node, lane=channel. Edge loop x4.
__global__ __launch_bounds__(256) void aggregate_kernel(
    const float* __restrict__ h, const float* __restrict__ sums,
    const float* __restrict__ bn_g, const float* __restrict__ bn_b,
    const int* __restrict__ rowstart, const int* __restrict__ csr_src,
    const float* __restrict__ ea_csr, const float* __restrict__ edge_W,
    const float* __restrict__ edge_b, const float* __restrict__ t,
    float* __restrict__ out, int n, float invN) {
  int lane = threadIdx.x & 63;
  int node = blockIdx.x * 4 + (threadIdx.x >> 6);
  if (node >= n) return;
  float ssum = 0.f, qsum = 0.f;
#pragma unroll
  for (int k = 0; k < 8; ++k) {
    ssum += sums[k * 128 + lane];
    qsum += sums[k * 128 + 64 + lane];
  }
  float mu = ssum * invN;
  float var = qsum * invN - mu * mu;
  float aa = rsqrtf(var + 1e-5f) * bn_g[lane];
  float cc = bn_b[lane] - mu * aa;
  float wcol[EDIM];
#pragma unroll
  for (int k = 0; k < EDIM; ++k) wcol[k] = edge_W[k * 64 + lane];
  float eb = edge_b[lane];
  float tt = t[0];
  int s0 = __builtin_amdgcn_readfirstlane(rowstart[node]);
  int s1 = __builtin_amdgcn_readfirstlane(rowstart[node + 1]);
  float hd = fmaxf(fmaf(h[(size_t)node * 64 + lane], aa, cc), 0.f);
  float den = 0.f, num = 0.f;
  for (int base = s0; base < s1; base += 64) {
    int myi = base + lane;
    int srcs = (myi < s1) ? csr_src[myi] : 0;
    int cnt = min(64, s1 - base);
    int jj = 0;
    for (; jj + 4 <= cnt; jj += 4) {
      int i0 = __shfl(srcs, jj, 64);
      int i1 = __shfl(srcs, jj + 1, 64);
      int i2 = __shfl(srcs, jj + 2, 64);
      int i3 = __shfl(srcs, jj + 3, 64);
      float hv0 = h[(size_t)i0 * 64 + lane];
      float hv1 = h[(size_t)i1 * 64 + lane];
      float hv2 = h[(size_t)i2 * 64 + lane];
      float hv3 = h[(size_t)i3 * 64 + lane];
      const float4* ep = (const float4*)(ea_csr + (size_t)(base + jj) * EDIM);
      float4 a0 = ep[0], c0 = ep[1], a1 = ep[2], c1 = ep[3];
      float4 a2 = ep[4], c2 = ep[5], a3 = ep[6], c3 = ep[7];
#define EDGE_STEP(HV, A, C)                                                   \
      {                                                                        \
        float ev = eb;                                                         \
        ev = fmaf(A.x, wcol[0], ev); ev = fmaf(A.y, wcol[1], ev);              \
        ev = fmaf(A.z, wcol[2], ev); ev = fmaf(A.w, wcol[3], ev);              \
        ev = fmaf(C.x, wcol[4], ev); ev = fmaf(C.y, wcol[5], ev);              \
        ev = fmaf(C.z, wcol[6], ev); ev = fmaf(C.w, wcol[7], ev);              \
        float hn = fmaxf(fmaf(HV, aa, cc), 0.f);                               \
        float msg = fmaxf(hn + ev, 0.f) + 1e-7f;                               \
        float p = __expf(msg * tt);                                            \
        den += p;                                                              \
        num = fmaf(p, msg, num);                                               \
      }
      EDGE_STEP(hv0, a0, c0)
      EDGE_STEP(hv1, a1, c1)
      EDGE_STEP(hv2, a2, c2)
      EDGE_STEP(hv3, a3, c3)
    }
    for (; jj < cnt; ++jj) {
      int si = __shfl(srcs, jj, 64);
      float hv = h[(size_t)si * 64 + lane];
      const float4* ep = (const float4*)(ea_csr + (size_t)(base + jj) * EDIM);
      float4 a0 = ep[0], c0 = ep[1];
      EDGE_STEP(hv, a0, c0)
    }
#undef EDGE_STEP
  }
  out[(size_t)node * 64 + lane] = num / fmaxf(den, 1e-16f) + hd;
}

// Tiled-GEMM MLP: 256 threads (4 waves), 64 nodes/block. Thread tile 4x8 (phase1)
// and 4x4 (phase2); LDS: xT/zT (stride 68) + weights; 68KB -> 2 blocks/CU = 8 waves.
__global__ __launch_bounds__(256) void mlp_tile_kernel(
    const float* __restrict__ outv, const float* __restrict__ h_in,
    const float* __restrict__ W1, const float* __restrict__ b1,
    const float* __restrict__ lng, const float* __restrict__ lnb,
    const float* __restrict__ W2, const float* __restrict__ b2,
    float* __restrict__ h_out, float* __restrict__ nextsums, int n) {
  __shared__ float bufA[128 * 68];  // xT[64][68] -> red zone -> zT[128][68]
  __shared__ float bufB[64 * 128];  // W1s then W2s
  __shared__ float mstat[128];      // mu[64], rstd[64]
  const int tid = threadIdx.x;
  const int tx = tid & 15, ty = tid >> 4;
  const int n0 = blockIdx.x * 64;
  // stage xT (transposed) + W1
#pragma unroll
  for (int i = 0; i < 16; ++i) {
    int gid = i * 256 + tid;
    int node = gid >> 6, c = gid & 63;
    int nd = n0 + node;
    bufA[c * 68 + node] = (nd < n) ? outv[(size_t)nd * 64 + c] : 0.f;
  }
  {
    const float4* w1g = (const float4*)W1;
    float4* w1s = (float4*)bufB;
#pragma unroll
    for (int i = 0; i < 8; ++i) w1s[i * 256 + tid] = w1g[i * 256 + tid];
  }
  __syncthreads();
  // ---- phase 1: y[4 nodes][8 ch] = x @ W1 + b1 ----
  const float4* b1v = (const float4*)b1;
  float4 acc0[4], acc1[4];
  {
    float4 bA = b1v[2 * ty], bB = b1v[2 * ty + 1];
#pragma unroll
    for (int i = 0; i < 4; ++i) { acc0[i] = bA; acc1[i] = bB; }
  }
  for (int k = 0; k < 64; ++k) {
    float4 xv = *(const float4*)&bufA[k * 68 + 4 * tx];
    float4 w0 = *(const float4*)&bufB[k * 128 + 8 * ty];
    float4 w1 = *(const float4*)&bufB[k * 128 + 8 * ty + 4];
#define FMA8(I, XS)                                                            \
    acc0[I].x = fmaf(XS, w0.x, acc0[I].x);                                     \
    acc0[I].y = fmaf(XS, w0.y, acc0[I].y);                                     \
    acc0[I].z = fmaf(XS, w0.z, acc0[I].z);                                     \
    acc0[I].w = fmaf(XS, w0.w, acc0[I].w);                                     \
    acc1[I].x = fmaf(XS, w1.x, acc1[I].x);                                     \
    acc1[I].y = fmaf(XS, w1.y, acc1[I].y);                                     \
    acc1[I].z = fmaf(XS, w1.z, acc1[I].z);                                     \
    acc1[I].w = fmaf(XS, w1.w, acc1[I].w);
    FMA8(0, xv.x) FMA8(1, xv.y) FMA8(2, xv.z) FMA8(3, xv.w)
#undef FMA8
  }
  // LN partials per (node, ty): safe region (rows 64+), no sync needed pre-store
  float* redS = bufA + 64 * 68;
  float* redQ = redS + 16 * 68;
#pragma unroll
  for (int i = 0; i < 4; ++i) {
    float si = ((acc0[i].x + acc0[i].y) + (acc0[i].z + acc0[i].w)) +
               ((acc1[i].x + acc1[i].y) + (acc1[i].z + acc1[i].w));
    float qi = 0.f;
    qi = fmaf(acc0[i].x, acc0[i].x, qi); qi = fmaf(acc0[i].y, acc0[i].y, qi);
    qi = fmaf(acc0[i].z, acc0[i].z, qi); qi = fmaf(acc0[i].w, acc0[i].w, qi);
    qi = fmaf(acc1[i].x, acc1[i].x, qi); qi = fmaf(acc1[i].y, acc1[i].y, qi);
    qi = fmaf(acc1[i].z, acc1[i].z, qi); qi = fmaf(acc1[i].w, acc1[i].w, qi);
    redS[ty * 68 + 4 * tx + i] = si;
    redQ[ty * 68 + 4 * tx + i] = qi;
  }
  __syncthreads();  // phase1 LDS reads + red stores complete
  // stage W2 (bufB free) while 64 threads compute mu/rstd
  {
    const float4* w2g = (const float4*)W2;
    float4* w2s = (float4*)bufB;
#pragma unroll
    for (int i = 0; i < 8; ++i) w2s[i * 256 + tid] = w2g[i * 256 + tid];
  }
  if (tid < 64) {
    float S = 0.f, Q = 0.f;
#pragma unroll
    for (int t = 0; t < 16; ++t) { S += redS[t * 68 + tid]; Q += redQ[t * 68 + tid]; }
    float mu = S * (1.f / 128.f);
    float var = Q * (1.f / 128.f) - mu * mu;
    mstat[tid] = mu;
    mstat[64 + tid] = rsqrtf(var + 1e-5f);
  }
  __syncthreads();
  // z = relu(LN(y)) written transposed into bufA rows 0..127
  {
    const float4* lgv = (const float4*)lng;
    const float4* lbv = (const float4*)lnb;
    float4 g0 = lgv[2 * ty], g1 = lgv[2 * ty + 1];
    float4 e0 = lbv[2 * ty], e1 = lbv[2 * ty + 1];
    float mu0 = mstat[4 * tx + 0], mu1 = mstat[4 * tx + 1];
    float mu2 = mstat[4 * tx + 2], mu3 = mstat[4 * tx + 3];
    float r0 = mstat[64 + 4 * tx + 0], r1 = mstat[64 + 4 * tx + 1];
    float r2 = mstat[64 + 4 * tx + 2], r3 = mstat[64 + 4 * tx + 3];
#define ZROW(ROW, A, C, G, E)                                                  \
    { float4 zr;                                                               \
      zr.x = fmaxf((A[0].C - mu0) * r0 * (G).C + (E).C, 0.f);                  \
      zr.y = fmaxf((A[1].C - mu1) * r1 * (G).C + (E).C, 0.f);                  \
      zr.z = fmaxf((A[2].C - mu2) * r2 * (G).C + (E).C, 0.f);                  \
      zr.w = fmaxf((A[3].C - mu3) * r3 * (G).C + (E).C, 0.f);                  \
      *(float4*)&bufA[(8 * ty + (ROW)) * 68 + 4 * tx] = zr; }
    ZROW(0, acc0, x, g0, e0)
    ZROW(1, acc0, y, g0, e0)
    ZROW(2, acc0, z, g0, e0)
    ZROW(3, acc0, w, g0, e0)
    ZROW(4, acc1, x, g1, e1)
    ZROW(5, acc1, y, g1, e1)
    ZROW(6, acc1, z, g1, e1)
    ZROW(7, acc1, w, g1, e1)
#undef ZROW
  }
  __syncthreads();
  // ---- phase 2: out[4 nodes][4 ch] = z @ W2 + b2 ----
  float4 oa[4];
  {
    float4 bc = ((const float4*)b2)[ty];
#pragma unroll
    for (int i = 0; i < 4; ++i) oa[i] = bc;
  }
  for (int k = 0; k < 128; ++k) {
    float4 zv = *(const float4*)&bufA[k * 68 + 4 * tx];
    float4 wv = *(const float4*)&bufB[k * 64 + 4 * ty];
#define P2(I, ZS)                                                              \
    oa[I].x = fmaf(ZS, wv.x, oa[I].x);                                         \
    oa[I].y = fmaf(ZS, wv.y, oa[I].y);                                         \
    oa[I].z = fmaf(ZS, wv.z, oa[I].z);                                         \
    oa[I].w = fmaf(ZS, wv.w, oa[I].w);
    P2(0, zv.x) P2(1, zv.y) P2(2, zv.z) P2(3, zv.w)
#undef P2
  }
  // residual + store + per-channel partials
  float4 ps = make_float4(0.f, 0.f, 0.f, 0.f);
  float4 pq = make_float4(0.f, 0.f, 0.f, 0.f);
#pragma unroll
  for (int i = 0; i < 4; ++i) {
    int nd = n0 + 4 * tx + i;
    if (nd < n) {
      float4 hv = *(const float4*)&h_in[(size_t)nd * 64 + 4 * ty];
      float4 v;
      v.x = hv.x + oa[i].x; v.y = hv.y + oa[i].y;
      v.z = hv.z + oa[i].z; v.w = hv.w + oa[i].w;
      *(float4*)&h_out[(size_t)nd * 64 + 4 * ty] = v;
      ps.x += v.x; ps.y += v.y; ps.z += v.z; ps.w += v.w;
      pq.x = fmaf(v.x, v.x, pq.x); pq.y = fmaf(v.y, v.y, pq.y);
      pq.z = fmaf(v.z, v.z, pq.z); pq.w = fmaf(v.w, v.w, pq.w);
    }
  }
  if (nextsums != nullptr) {
    __syncthreads();  // phase2 zT reads done; bufA free
    float* rs = bufA;             // [64 ch][17]
    float* rq = bufA + 64 * 17;
    rs[(4 * ty + 0) * 17 + tx] = ps.x;
    rs[(4 * ty + 1) * 17 + tx] = ps.y;
    rs[(4 * ty + 2) * 17 + tx] = ps.z;
    rs[(4 * ty + 3) * 17 + tx] = ps.w;
    rq[(4 * ty + 0) * 17 + tx] = pq.x;
    rq[(4 * ty + 1) * 17 + tx] = pq.y;
    rq[(4 * ty + 2) * 17 + tx] = pq.z;
    rq[(4 * ty + 3) * 17 + tx] = pq.w;
    __syncthreads();
    if (tid < 64) {
      float S = 0.f, Q = 0.f;
#pragma unroll
      for (int t = 0; t < 16; ++t) { S += rs[tid * 17 + t]; Q += rq[tid * 17 + t]; }
      int slot = blockIdx.x & 7;
      atomicAdd(&nextsums[slot * 128 + tid], S);
      atomicAdd(&nextsums[slot * 128 + 64 + tid], Q);
    }
  }
}

extern "C" void kernel_launch(void* const* d_in, const int* in_sizes, int n_in,
                              void* d_out, int out_size, void* d_ws, size_t ws_size,
                              hipStream_t stream) {
  const float* x = (const float*)d_in[0];
  const int* edge_index = (const int*)d_in[1];
  const float* edge_attr = (const float*)d_in[2];
  const float* node_W = (const float*)d_in[3];
  const float* node_b = (const float*)d_in[4];
  const float* edge_W = (const float*)d_in[5];
  const float* edge_b = (const float*)d_in[6];
  const float* bn_g = (const float*)d_in[7];
  const float* bn_b = (const float*)d_in[8];
  const float* t = (const float*)d_in[9];
  const float* W1 = (const float*)d_in[10];
  const float* b1 = (const float*)d_in[11];
  const float* ln_g = (const float*)d_in[12];
  const float* ln_b = (const float*)d_in[13];
  const float* W2 = (const float*)d_in[14];
  const float* b2 = (const float*)d_in[15];

  int N = in_sizes[0] / HDIM;
  int E = in_sizes[1] / 2;
  const int* srcp = edge_index;
  const int* dstp = edge_index + E;

  char* ws = (char*)d_ws;
  size_t off = 0;
  auto alloc = [&](size_t bytes) {
    char* p = ws + off;
    off = (off + bytes + 255) & ~(size_t)255;
    return p;
  };
  int* deg = (int*)alloc((size_t)N * 4);
  int* rowstart = (int*)alloc(((size_t)N + 1) * 4);
  int* fillptr = (int*)alloc((size_t)N * 4);
  int* partials = (int*)alloc(1024 * 4);
  float* bnsums = (float*)alloc(3 * 1024 * 4);  // 3 layers x 8 slots x 128
  int* csr_src = (int*)alloc((size_t)E * 4);
  float* ea_csr = (float*)alloc((size_t)E * EDIM * 4);
  float* h = (float*)alloc((size_t)N * 64 * 4);
  float* outv = (float*)alloc((size_t)N * 64 * 4);
  (void)ws_size; (void)n_in; (void)out_size;

  int nb = (N + 255) / 256;  // 196 partial blocks
  hipMemsetAsync(bnsums, 0, 3 * 1024 * 4, stream);
  init_h_stats_kernel<<<512, 256, 0, stream>>>(x, node_W, node_b, h, bnsums, deg, N);
  deg_kernel<<<(E + 255) / 256, 256, 0, stream>>>(dstp, deg, E);
  scan_part_kernel<<<nb, 256, 0, stream>>>(deg, partials, N);
  scan_top_kernel<<<1, 1024, 0, stream>>>(partials, nb);
  scan_fill_kernel<<<nb, 256, 0, stream>>>(deg, partials, rowstart, fillptr, N, E);
  fill_kernel<<<(E + 255) / 256, 256, 0, stream>>>(srcp, dstp, edge_attr, fillptr, csr_src, ea_csr, E);

  float invN = 1.0f / (float)N;
  int mlp_blocks = (N + 63) / 64;
  for (int l = 0; l < 3; ++l) {
    aggregate_kernel<<<(N + 3) / 4, 256, 0, stream>>>(
        h, bnsums + l * 1024, bn_g + l * 64, bn_b + l * 64, rowstart, csr_src, ea_csr,
        edge_W, edge_b, t + l, outv, N, invN);
    float* hout = (l == 2) ? (float*)d_out : h;
    float* nxt = (l == 2) ? nullptr : (bnsums + (l + 1) * 1024);
    mlp_tile_kernel<<<mlp_blocks, 256, 0, stream>>>(outv, h, W1 + (size_t)l * 8192, b1 + l * 128,
                                                    ln_g + l * 128, ln_b + l * 128,
                                                    W2 + (size_t)l * 8192, b2 + l * 64, hout, nxt, N);
  }
}

// Round 10
// 334.917 us; speedup vs baseline: 7.9182x; 1.0793x over previous
//
#include <hip/hip_runtime.h>
#include <hip/hip_bf16.h>
#include <hip/hip_fp16.h>

constexpr int HDIM = 8;
constexpr int EDIM = 8;

__device__ __forceinline__ unsigned pack2h(float a, float b) {
  __half2 h = __floats2half2_rn(a, b);
  union { __half2 h2; unsigned u; } u;
  u.h2 = h;
  return u.u;
}

__device__ __forceinline__ float2 unpack2h(unsigned v) {
  union { unsigned u; __half2 h2; } u;
  u.u = v;
  return __half22float2(u.h2);
}

// h = x @ node_W + node_b, fused with layer-0 BN stats (8-slot) and deg zeroing.
__global__ __launch_bounds__(256) void init_h_stats_kernel(
    const float* __restrict__ x, const float* __restrict__ W, const float* __restrict__ b,
    float* __restrict__ h, float* __restrict__ sums, int* __restrict__ deg, int n) {
  __shared__ float reds[256], redq[256];
  int tid = threadIdx.x, lane = tid & 63;
  int gtid = blockIdx.x * 256 + tid;
  for (int i = gtid; i < n; i += 512 * 256) deg[i] = 0;
  float wc[HDIM];
#pragma unroll
  for (int k = 0; k < HDIM; ++k) wc[k] = W[k * 64 + lane];
  float bc = b[lane];
  float s = 0.f, q = 0.f;
  int total = n * 64;
  for (int gid = gtid; gid < total; gid += 512 * 256) {
    int row = gid >> 6;
    const float* xr = x + (size_t)row * HDIM;
    float acc = bc;
#pragma unroll
    for (int k = 0; k < HDIM; ++k) acc = fmaf(xr[k], wc[k], acc);
    h[gid] = acc;
    s += acc;
    q = fmaf(acc, acc, q);
  }
  reds[tid] = s; redq[tid] = q;
  __syncthreads();
  if (tid < 64) {
    float S = reds[tid] + reds[64 + tid] + reds[128 + tid] + reds[192 + tid];
    float Q = redq[tid] + redq[64 + tid] + redq[128 + tid] + redq[192 + tid];
    int slot = blockIdx.x & 7;
    atomicAdd(&sums[slot * 128 + tid], S);
    atomicAdd(&sums[slot * 128 + 64 + tid], Q);
  }
}

// degree histogram + per-edge within-dst index (removes fill's atomics)
__global__ void deg_kernel(const int* __restrict__ dst, int* __restrict__ deg,
                           int* __restrict__ idxw, int E) {
  int e = blockIdx.x * 256 + threadIdx.x;
  if (e < E) idxw[e] = atomicAdd(&deg[dst[e]], 1);
}

// 3-dispatch device-wide exclusive scan
__global__ __launch_bounds__(256) void scan_part_kernel(const int* __restrict__ deg,
                                                        int* __restrict__ partials, int n) {
  __shared__ int sh[256];
  int tid = threadIdx.x, idx = blockIdx.x * 256 + tid;
  int v = (idx < n) ? deg[idx] : 0;
  sh[tid] = v;
  __syncthreads();
  for (int o = 128; o > 0; o >>= 1) {
    if (tid < o) sh[tid] += sh[tid + o];
    __syncthreads();
  }
  if (tid == 0) partials[blockIdx.x] = sh[0];
}

__global__ __launch_bounds__(1024) void scan_top_kernel(int* __restrict__ partials, int nb) {
  __shared__ int sh[1024];
  int tid = threadIdx.x;
  int v = (tid < nb) ? partials[tid] : 0;
  sh[tid] = v;
  __syncthreads();
  for (int o = 1; o < 1024; o <<= 1) {
    int a = (tid >= o) ? sh[tid - o] : 0;
    __syncthreads();
    sh[tid] += a;
    __syncthreads();
  }
  if (tid < nb) partials[tid] = sh[tid] - v;  // exclusive
}

__global__ __launch_bounds__(256) void scan_fill_kernel(
    const int* __restrict__ deg, const int* __restrict__ partials,
    int* __restrict__ rowstart, int n, int total) {
  __shared__ int sh[256];
  int tid = threadIdx.x, idx = blockIdx.x * 256 + tid;
  int v = (idx < n) ? deg[idx] : 0;
  sh[tid] = v;
  __syncthreads();
  for (int o = 1; o < 256; o <<= 1) {
    int a = (tid >= o) ? sh[tid - o] : 0;
    __syncthreads();
    sh[tid] += a;
    __syncthreads();
  }
  if (idx < n) rowstart[idx] = partials[blockIdx.x] + sh[tid] - v;
  if (blockIdx.x == 0 && tid == 0) rowstart[n] = total;
}

// scatter ONE 32B record per edge: {f16 ea[8] (16B), src (4B), pad}. No atomics.
__global__ void fill_kernel(const int* __restrict__ src, const int* __restrict__ dst,
                            const int* __restrict__ idxw, const int* __restrict__ rowstart,
                            const float* __restrict__ edge_attr, char* __restrict__ recs, int E) {
  int e = blockIdx.x * 256 + threadIdx.x;
  if (e >= E) return;
  int d = dst[e];
  int slot = rowstart[d] + idxw[e];
  const float4* ap = (const float4*)(edge_attr + (size_t)e * EDIM);
  float4 a = ap[0], c = ap[1];
  uint4 rv;
  rv.x = pack2h(a.x, a.y);
  rv.y = pack2h(a.z, a.w);
  rv.z = pack2h(c.x, c.y);
  rv.w = pack2h(c.z, c.w);
  char* rb = recs + (size_t)slot * 32;
  *(uint4*)rb = rv;
  *(int*)(rb + 16) = src[e];
}

// Fused BN+ReLU + message + softmax-agg. 1 wave/node, lane=channel. Edge loop x4.
__global__ __launch_bounds__(256) void aggregate_kernel(
    const float* __restrict__ h, const float* __restrict__ sums,
    const float* __restrict__ bn_g, const float* __restrict__ bn_b,
    const int* __restrict__ rowstart, const char* __restrict__ recs,
    const float* __restrict__ edge_W, const float* __restrict__ edge_b,
    const float* __restrict__ t, float* __restrict__ out, int n, float invN) {
  int lane = threadIdx.x & 63;
  int node = blockIdx.x * 4 + (threadIdx.x >> 6);
  if (node >= n) return;
  float ssum = 0.f, qsum = 0.f;
#pragma unroll
  for (int k = 0; k < 8; ++k) {
    ssum += sums[k * 128 + lane];
    qsum += sums[k * 128 + 64 + lane];
  }
  float mu = ssum * invN;
  float var = qsum * invN - mu * mu;
  float aa = rsqrtf(var + 1e-5f) * bn_g[lane];
  float cc = bn_b[lane] - mu * aa;
  float wcol[EDIM];
#pragma unroll
  for (int k = 0; k < EDIM; ++k) wcol[k] = edge_W[k * 64 + lane];
  float eb = edge_b[lane];
  float tt = t[0];
  int s0 = __builtin_amdgcn_readfirstlane(rowstart[node]);
  int s1 = __builtin_amdgcn_readfirstlane(rowstart[node + 1]);
  float hd = fmaxf(fmaf(h[(size_t)node * 64 + lane], aa, cc), 0.f);
  float den = 0.f, num = 0.f;
#define EDGE_STEP(HV, RV)                                                      \
  {                                                                            \
    float2 f0 = unpack2h(RV.x), f1 = unpack2h(RV.y);                           \
    float2 f2 = unpack2h(RV.z), f3 = unpack2h(RV.w);                           \
    float ev = eb;                                                             \
    ev = fmaf(f0.x, wcol[0], ev); ev = fmaf(f0.y, wcol[1], ev);                \
    ev = fmaf(f1.x, wcol[2], ev); ev = fmaf(f1.y, wcol[3], ev);                \
    ev = fmaf(f2.x, wcol[4], ev); ev = fmaf(f2.y, wcol[5], ev);                \
    ev = fmaf(f3.x, wcol[6], ev); ev = fmaf(f3.y, wcol[7], ev);                \
    float hn = fmaxf(fmaf(HV, aa, cc), 0.f);                                   \
    float msg = fmaxf(hn + ev, 0.f) + 1e-7f;                                   \
    float p = __expf(msg * tt);                                                \
    den += p;                                                                  \
    num = fmaf(p, msg, num);                                                   \
  }
  int j = s0;
  for (; j + 4 <= s1; j += 4) {
    const char* rb = recs + (size_t)j * 32;
    uint4 r0 = *(const uint4*)(rb);
    uint4 r1 = *(const uint4*)(rb + 32);
    uint4 r2 = *(const uint4*)(rb + 64);
    uint4 r3 = *(const uint4*)(rb + 96);
    int i0 = *(const int*)(rb + 16);
    int i1 = *(const int*)(rb + 48);
    int i2 = *(const int*)(rb + 80);
    int i3 = *(const int*)(rb + 112);
    float hv0 = h[(size_t)i0 * 64 + lane];
    float hv1 = h[(size_t)i1 * 64 + lane];
    float hv2 = h[(size_t)i2 * 64 + lane];
    float hv3 = h[(size_t)i3 * 64 + lane];
    EDGE_STEP(hv0, r0)
    EDGE_STEP(hv1, r1)
    EDGE_STEP(hv2, r2)
    EDGE_STEP(hv3, r3)
  }
  for (; j < s1; ++j) {
    const char* rb = recs + (size_t)j * 32;
    uint4 r0 = *(const uint4*)(rb);
    int i0 = *(const int*)(rb + 16);
    float hv = h[(size_t)i0 * 64 + lane];
    EDGE_STEP(hv, r0)
  }
#undef EDGE_STEP
  out[(size_t)node * 64 + lane] = num / fmaxf(den, 1e-16f) + hd;
}

// Tiled-GEMM MLP: 256 threads (4 waves), 64 nodes/block. Thread tile 4x8 (phase1)
// and 4x4 (phase2); LDS: xT/zT (stride 68) + weights; 68KB -> 2 blocks/CU = 8 waves.
__global__ __launch_bounds__(256) void mlp_tile_kernel(
    const float* __restrict__ outv, const float* __restrict__ h_in,
    const float* __restrict__ W1, const float* __restrict__ b1,
    const float* __restrict__ lng, const float* __restrict__ lnb,
    const float* __restrict__ W2, const float* __restrict__ b2,
    float* __restrict__ h_out, float* __restrict__ nextsums, int n) {
  __shared__ float bufA[128 * 68];  // xT[64][68] -> red zone -> zT[128][68]
  __shared__ float bufB[64 * 128];  // W1s then W2s
  __shared__ float mstat[128];      // mu[64], rstd[64]
  const int tid = threadIdx.x;
  const int tx = tid & 15, ty = tid >> 4;
  const int n0 = blockIdx.x * 64;
#pragma unroll
  for (int i = 0; i < 16; ++i) {
    int gid = i * 256 + tid;
    int node = gid >> 6, c = gid & 63;
    int nd = n0 + node;
    bufA[c * 68 + node] = (nd < n) ? outv[(size_t)nd * 64 + c] : 0.f;
  }
  {
    const float4* w1g = (const float4*)W1;
    float4* w1s = (float4*)bufB;
#pragma unroll
    for (int i = 0; i < 8; ++i) w1s[i * 256 + tid] = w1g[i * 256 + tid];
  }
  __syncthreads();
  const float4* b1v = (const float4*)b1;
  float4 acc0[4], acc1[4];
  {
    float4 bA = b1v[2 * ty], bB = b1v[2 * ty + 1];
#pragma unroll
    for (int i = 0; i < 4; ++i) { acc0[i] = bA; acc1[i] = bB; }
  }
  for (int k = 0; k < 64; ++k) {
    float4 xv = *(const float4*)&bufA[k * 68 + 4 * tx];
    float4 w0 = *(const float4*)&bufB[k * 128 + 8 * ty];
    float4 w1 = *(const float4*)&bufB[k * 128 + 8 * ty + 4];
#define FMA8(I, XS)                                                            \
    acc0[I].x = fmaf(XS, w0.x, acc0[I].x);                                     \
    acc0[I].y = fmaf(XS, w0.y, acc0[I].y);                                     \
    acc0[I].z = fmaf(XS, w0.z, acc0[I].z);                                     \
    acc0[I].w = fmaf(XS, w0.w, acc0[I].w);                                     \
    acc1[I].x = fmaf(XS, w1.x, acc1[I].x);                                     \
    acc1[I].y = fmaf(XS, w1.y, acc1[I].y);                                     \
    acc1[I].z = fmaf(XS, w1.z, acc1[I].z);                                     \
    acc1[I].w = fmaf(XS, w1.w, acc1[I].w);
    FMA8(0, xv.x) FMA8(1, xv.y) FMA8(2, xv.z) FMA8(3, xv.w)
#undef FMA8
  }
  float* redS = bufA + 64 * 68;
  float* redQ = redS + 16 * 68;
#pragma unroll
  for (int i = 0; i < 4; ++i) {
    float si = ((acc0[i].x + acc0[i].y) + (acc0[i].z + acc0[i].w)) +
               ((acc1[i].x + acc1[i].y) + (acc1[i].z + acc1[i].w));
    float qi = 0.f;
    qi = fmaf(acc0[i].x, acc0[i].x, qi); qi = fmaf(acc0[i].y, acc0[i].y, qi);
    qi = fmaf(acc0[i].z, acc0[i].z, qi); qi = fmaf(acc0[i].w, acc0[i].w, qi);
    qi = fmaf(acc1[i].x, acc1[i].x, qi); qi = fmaf(acc1[i].y, acc1[i].y, qi);
    qi = fmaf(acc1[i].z, acc1[i].z, qi); qi = fmaf(acc1[i].w, acc1[i].w, qi);
    redS[ty * 68 + 4 * tx + i] = si;
    redQ[ty * 68 + 4 * tx + i] = qi;
  }
  __syncthreads();
  {
    const float4* w2g = (const float4*)W2;
    float4* w2s = (float4*)bufB;
#pragma unroll
    for (int i = 0; i < 8; ++i) w2s[i * 256 + tid] = w2g[i * 256 + tid];
  }
  if (tid < 64) {
    float S = 0.f, Q = 0.f;
#pragma unroll
    for (int t = 0; t < 16; ++t) { S += redS[t * 68 + tid]; Q += redQ[t * 68 + tid]; }
    float mu = S * (1.f / 128.f);
    float var = Q * (1.f / 128.f) - mu * mu;
    mstat[tid] = mu;
    mstat[64 + tid] = rsqrtf(var + 1e-5f);
  }
  __syncthreads();
  {
    const float4* lgv = (const float4*)lng;
    const float4* lbv = (const float4*)lnb;
    float4 g0 = lgv[2 * ty], g1 = lgv[2 * ty + 1];
    float4 e0 = lbv[2 * ty], e1 = lbv[2 * ty + 1];
    float mu0 = mstat[4 * tx + 0], mu1 = mstat[4 * tx + 1];
    float mu2 = mstat[4 * tx + 2], mu3 = mstat[4 * tx + 3];
    float r0 = mstat[64 + 4 * tx + 0], r1 = mstat[64 + 4 * tx + 1];
    float r2 = mstat[64 + 4 * tx + 2], r3 = mstat[64 + 4 * tx + 3];
#define ZROW(ROW, A, C, G, E)                                                  \
    { float4 zr;                                                               \
      zr.x = fmaxf((A[0].C - mu0) * r0 * (G).C + (E).C, 0.f);                  \
      zr.y = fmaxf((A[1].C - mu1) * r1 * (G).C + (E).C, 0.f);                  \
      zr.z = fmaxf((A[2].C - mu2) * r2 * (G).C + (E).C, 0.f);                  \
      zr.w = fmaxf((A[3].C - mu3) * r3 * (G).C + (E).C, 0.f);                  \
      *(float4*)&bufA[(8 * ty + (ROW)) * 68 + 4 * tx] = zr; }
    ZROW(0, acc0, x, g0, e0)
    ZROW(1, acc0, y, g0, e0)
    ZROW(2, acc0, z, g0, e0)
    ZROW(3, acc0, w, g0, e0)
    ZROW(4, acc1, x, g1, e1)
    ZROW(5, acc1, y, g1, e1)
    ZROW(6, acc1, z, g1, e1)
    ZROW(7, acc1, w, g1, e1)
#undef ZROW
  }
  __syncthreads();
  float4 oa[4];
  {
    float4 bc = ((const float4*)b2)[ty];
#pragma unroll
    for (int i = 0; i < 4; ++i) oa[i] = bc;
  }
  for (int k = 0; k < 128; ++k) {
    float4 zv = *(const float4*)&bufA[k * 68 + 4 * tx];
    float4 wv = *(const float4*)&bufB[k * 64 + 4 * ty];
#define P2(I, ZS)                                                              \
    oa[I].x = fmaf(ZS, wv.x, oa[I].x);                                         \
    oa[I].y = fmaf(ZS, wv.y, oa[I].y);                                         \
    oa[I].z = fmaf(ZS, wv.z, oa[I].z);                                         \
    oa[I].w = fmaf(ZS, wv.w, oa[I].w);
    P2(0, zv.x) P2(1, zv.y) P2(2, zv.z) P2(3, zv.w)
#undef P2
  }
  float4 ps = make_float4(0.f, 0.f, 0.f, 0.f);
  float4 pq = make_float4(0.f, 0.f, 0.f, 0.f);
#pragma unroll
  for (int i = 0; i < 4; ++i) {
    int nd = n0 + 4 * tx + i;
    if (nd < n) {
      float4 hv = *(const float4*)&h_in[(size_t)nd * 64 + 4 * ty];
      float4 v;
      v.x = hv.x + oa[i].x; v.y = hv.y + oa[i].y;
      v.z = hv.z + oa[i].z; v.w = hv.w + oa[i].w;
      *(float4*)&h_out[(size_t)nd * 64 + 4 * ty] = v;
      ps.x += v.x; ps.y += v.y; ps.z += v.z; ps.w += v.w;
      pq.x = fmaf(v.x, v.x, pq.x); pq.y = fmaf(v.y, v.y, pq.y);
      pq.z = fmaf(v.z, v.z, pq.z); pq.w = fmaf(v.w, v.w, pq.w);
    }
  }
  if (nextsums != nullptr) {
    __syncthreads();
    float* rs = bufA;
    float* rq = bufA + 64 * 17;
    rs[(4 * ty + 0) * 17 + tx] = ps.x;
    rs[(4 * ty + 1) * 17 + tx] = ps.y;
    rs[(4 * ty + 2) * 17 + tx] = ps.z;
    rs[(4 * ty + 3) * 17 + tx] = ps.w;
    rq[(4 * ty + 0) * 17 + tx] = pq.x;
    rq[(4 * ty + 1) * 17 + tx] = pq.y;
    rq[(4 * ty + 2) * 17 + tx] = pq.z;
    rq[(4 * ty + 3) * 17 + tx] = pq.w;
    __syncthreads();
    if (tid < 64) {
      float S = 0.f, Q = 0.f;
#pragma unroll
      for (int t = 0; t < 16; ++t) { S += rs[tid * 17 + t]; Q += rq[tid * 17 + t]; }
      int slot = blockIdx.x & 7;
      atomicAdd(&nextsums[slot * 128 + tid], S);
      atomicAdd(&nextsums[slot * 128 + 64 + tid], Q);
    }
  }
}

extern "C" void kernel_launch(void* const* d_in, const int* in_sizes, int n_in,
                              void* d_out, int out_size, void* d_ws, size_t ws_size,
                              hipStream_t stream) {
  const float* x = (const float*)d_in[0];
  const int* edge_index = (const int*)d_in[1];
  const float* edge_attr = (const float*)d_in[2];
  const float* node_W = (const float*)d_in[3];
  const float* node_b = (const float*)d_in[4];
  const float* edge_W = (const float*)d_in[5];
  const float* edge_b = (const float*)d_in[6];
  const float* bn_g = (const float*)d_in[7];
  const float* bn_b = (const float*)d_in[8];
  const float* t = (const float*)d_in[9];
  const float* W1 = (const float*)d_in[10];
  const float* b1 = (const float*)d_in[11];
  const float* ln_g = (const float*)d_in[12];
  const float* ln_b = (const float*)d_in[13];
  const float* W2 = (const float*)d_in[14];
  const float* b2 = (const float*)d_in[15];

  int N = in_sizes[0] / HDIM;
  int E = in_sizes[1] / 2;
  const int* srcp = edge_index;
  const int* dstp = edge_index + E;

  char* ws = (char*)d_ws;
  size_t off = 0;
  auto alloc = [&](size_t bytes) {
    char* p = ws + off;
    off = (off + bytes + 255) & ~(size_t)255;
    return p;
  };
  int* deg = (int*)alloc((size_t)N * 4);
  int* rowstart = (int*)alloc(((size_t)N + 1) * 4);
  int* idxw = (int*)alloc((size_t)E * 4);
  int* partials = (int*)alloc(1024 * 4);
  float* bnsums = (float*)alloc(3 * 1024 * 4);  // 3 layers x 8 slots x 128
  char* recs = (char*)alloc((size_t)E * 32);
  float* h = (float*)alloc((size_t)N * 64 * 4);
  float* outv = (float*)alloc((size_t)N * 64 * 4);
  (void)ws_size; (void)n_in; (void)out_size;

  int nb = (N + 255) / 256;
  hipMemsetAsync(bnsums, 0, 3 * 1024 * 4, stream);
  init_h_stats_kernel<<<512, 256, 0, stream>>>(x, node_W, node_b, h, bnsums, deg, N);
  deg_kernel<<<(E + 255) / 256, 256, 0, stream>>>(dstp, deg, idxw, E);
  scan_part_kernel<<<nb, 256, 0, stream>>>(deg, partials, N);
  scan_top_kernel<<<1, 1024, 0, stream>>>(partials, nb);
  scan_fill_kernel<<<nb, 256, 0, stream>>>(deg, partials, rowstart, N, E);
  fill_kernel<<<(E + 255) / 256, 256, 0, stream>>>(srcp, dstp, idxw, rowstart, edge_attr, recs, E);

  float invN = 1.0f / (float)N;
  int mlp_blocks = (N + 63) / 64;
  for (int l = 0; l < 3; ++l) {
    aggregate_kernel<<<(N + 3) / 4, 256, 0, stream>>>(
        h, bnsums + l * 1024, bn_g + l * 64, bn_b + l * 64, rowstart, recs,
        edge_W, edge_b, t + l, outv, N, invN);
    float* hout = (l == 2) ? (float*)d_out : h;
    float* nxt = (l == 2) ? nullptr : (bnsums + (l + 1) * 1024);
    mlp_tile_kernel<<<mlp_blocks, 256, 0, stream>>>(outv, h, W1 + (size_t)l * 8192, b1 + l * 128,
                                                    ln_g + l * 128, ln_b + l * 128,
                                                    W2 + (size_t)l * 8192, b2 + l * 64, hout, nxt, N);
  }
}

// Round 11
// 314.973 us; speedup vs baseline: 8.4196x; 1.0633x over previous
//
#include <hip/hip_runtime.h>
#include <hip/hip_bf16.h>
#include <hip/hip_fp16.h>

constexpr int HDIM = 8;
constexpr int EDIM = 8;

__device__ __forceinline__ unsigned pack2h(float a, float b) {
  __half2 h = __floats2half2_rn(a, b);
  union { __half2 h2; unsigned u; } u;
  u.h2 = h;
  return u.u;
}

__device__ __forceinline__ float2 unpack2h(unsigned v) {
  union { unsigned u; __half2 h2; } u;
  u.u = v;
  return __half22float2(u.h2);
}

// h = x @ node_W + node_b, fused with layer-0 BN stats (8-slot) and deg zeroing.
__global__ __launch_bounds__(256) void init_h_stats_kernel(
    const float* __restrict__ x, const float* __restrict__ W, const float* __restrict__ b,
    float* __restrict__ h, float* __restrict__ sums, int* __restrict__ deg, int n) {
  __shared__ float reds[256], redq[256];
  int tid = threadIdx.x, lane = tid & 63;
  int gtid = blockIdx.x * 256 + tid;
  for (int i = gtid; i < n; i += 512 * 256) deg[i] = 0;
  float wc[HDIM];
#pragma unroll
  for (int k = 0; k < HDIM; ++k) wc[k] = W[k * 64 + lane];
  float bc = b[lane];
  float s = 0.f, q = 0.f;
  int total = n * 64;
  for (int gid = gtid; gid < total; gid += 512 * 256) {
    int row = gid >> 6;
    const float* xr = x + (size_t)row * HDIM;
    float acc = bc;
#pragma unroll
    for (int k = 0; k < HDIM; ++k) acc = fmaf(xr[k], wc[k], acc);
    h[gid] = acc;
    s += acc;
    q = fmaf(acc, acc, q);
  }
  reds[tid] = s; redq[tid] = q;
  __syncthreads();
  if (tid < 64) {
    float S = reds[tid] + reds[64 + tid] + reds[128 + tid] + reds[192 + tid];
    float Q = redq[tid] + redq[64 + tid] + redq[128 + tid] + redq[192 + tid];
    int slot = blockIdx.x & 7;
    atomicAdd(&sums[slot * 128 + tid], S);
    atomicAdd(&sums[slot * 128 + 64 + tid], Q);
  }
}

// degree histogram + per-edge within-dst index (removes fill's atomics)
__global__ void deg_kernel(const int* __restrict__ dst, int* __restrict__ deg,
                           int* __restrict__ idxw, int E) {
  int e = blockIdx.x * 256 + threadIdx.x;
  if (e < E) idxw[e] = atomicAdd(&deg[dst[e]], 1);
}

// 3-dispatch device-wide exclusive scan
__global__ __launch_bounds__(256) void scan_part_kernel(const int* __restrict__ deg,
                                                        int* __restrict__ partials, int n) {
  __shared__ int sh[256];
  int tid = threadIdx.x, idx = blockIdx.x * 256 + tid;
  int v = (idx < n) ? deg[idx] : 0;
  sh[tid] = v;
  __syncthreads();
  for (int o = 128; o > 0; o >>= 1) {
    if (tid < o) sh[tid] += sh[tid + o];
    __syncthreads();
  }
  if (tid == 0) partials[blockIdx.x] = sh[0];
}

__global__ __launch_bounds__(1024) void scan_top_kernel(int* __restrict__ partials, int nb) {
  __shared__ int sh[1024];
  int tid = threadIdx.x;
  int v = (tid < nb) ? partials[tid] : 0;
  sh[tid] = v;
  __syncthreads();
  for (int o = 1; o < 1024; o <<= 1) {
    int a = (tid >= o) ? sh[tid - o] : 0;
    __syncthreads();
    sh[tid] += a;
    __syncthreads();
  }
  if (tid < nb) partials[tid] = sh[tid] - v;  // exclusive
}

__global__ __launch_bounds__(256) void scan_fill_kernel(
    const int* __restrict__ deg, const int* __restrict__ partials,
    int* __restrict__ rowstart, int n, int total) {
  __shared__ int sh[256];
  int tid = threadIdx.x, idx = blockIdx.x * 256 + tid;
  int v = (idx < n) ? deg[idx] : 0;
  sh[tid] = v;
  __syncthreads();
  for (int o = 1; o < 256; o <<= 1) {
    int a = (tid >= o) ? sh[tid - o] : 0;
    __syncthreads();
    sh[tid] += a;
    __syncthreads();
  }
  if (idx < n) rowstart[idx] = partials[blockIdx.x] + sh[tid] - v;
  if (blockIdx.x == 0 && tid == 0) rowstart[n] = total;
}

// scatter ONE 32B record per edge: {f16 ea[8] (16B), src (4B), pad}. No atomics.
__global__ void fill_kernel(const int* __restrict__ src, const int* __restrict__ dst,
                            const int* __restrict__ idxw, const int* __restrict__ rowstart,
                            const float* __restrict__ edge_attr, char* __restrict__ recs, int E) {
  int e = blockIdx.x * 256 + threadIdx.x;
  if (e >= E) return;
  int d = dst[e];
  int slot = rowstart[d] + idxw[e];
  const float4* ap = (const float4*)(edge_attr + (size_t)e * EDIM);
  float4 a = ap[0], c = ap[1];
  uint4 rv;
  rv.x = pack2h(a.x, a.y);
  rv.y = pack2h(a.z, a.w);
  rv.z = pack2h(c.x, c.y);
  rv.w = pack2h(c.z, c.w);
  char* rb = recs + (size_t)slot * 32;
  *(uint4*)rb = rv;
  *(int*)(rb + 16) = src[e];
}

// Fused BN+ReLU + message + softmax-agg. 1 wave/node, lane=channel. Edge loop x8.
__global__ __launch_bounds__(256) void aggregate_kernel(
    const float* __restrict__ h, const float* __restrict__ sums,
    const float* __restrict__ bn_g, const float* __restrict__ bn_b,
    const int* __restrict__ rowstart, const char* __restrict__ recs,
    const float* __restrict__ edge_W, const float* __restrict__ edge_b,
    const float* __restrict__ t, float* __restrict__ out, int n, float invN) {
  int lane = threadIdx.x & 63;
  int node = blockIdx.x * 4 + (threadIdx.x >> 6);
  if (node >= n) return;
  float ssum = 0.f, qsum = 0.f;
#pragma unroll
  for (int k = 0; k < 8; ++k) {
    ssum += sums[k * 128 + lane];
    qsum += sums[k * 128 + 64 + lane];
  }
  float mu = ssum * invN;
  float var = qsum * invN - mu * mu;
  float aa = rsqrtf(var + 1e-5f) * bn_g[lane];
  float cc = bn_b[lane] - mu * aa;
  float wcol[EDIM];
#pragma unroll
  for (int k = 0; k < EDIM; ++k) wcol[k] = edge_W[k * 64 + lane];
  float eb = edge_b[lane];
  float tt = t[0];
  int s0 = __builtin_amdgcn_readfirstlane(rowstart[node]);
  int s1 = __builtin_amdgcn_readfirstlane(rowstart[node + 1]);
  float hd = fmaxf(fmaf(h[(size_t)node * 64 + lane], aa, cc), 0.f);
  float den = 0.f, num = 0.f;
#define EDGE_STEP(HV, RV)                                                      \
  {                                                                            \
    float2 f0 = unpack2h(RV.x), f1 = unpack2h(RV.y);                           \
    float2 f2 = unpack2h(RV.z), f3 = unpack2h(RV.w);                           \
    float ev = eb;                                                             \
    ev = fmaf(f0.x, wcol[0], ev); ev = fmaf(f0.y, wcol[1], ev);                \
    ev = fmaf(f1.x, wcol[2], ev); ev = fmaf(f1.y, wcol[3], ev);                \
    ev = fmaf(f2.x, wcol[4], ev); ev = fmaf(f2.y, wcol[5], ev);                \
    ev = fmaf(f3.x, wcol[6], ev); ev = fmaf(f3.y, wcol[7], ev);                \
    float hn = fmaxf(fmaf(HV, aa, cc), 0.f);                                   \
    float msg = fmaxf(hn + ev, 0.f) + 1e-7f;                                   \
    float p = __expf(msg * tt);                                                \
    den += p;                                                                  \
    num = fmaf(p, msg, num);                                                   \
  }
  int j = s0;
  for (; j + 8 <= s1; j += 8) {
    const char* rb = recs + (size_t)j * 32;
    uint4 r0 = *(const uint4*)(rb);
    uint4 r1 = *(const uint4*)(rb + 32);
    uint4 r2 = *(const uint4*)(rb + 64);
    uint4 r3 = *(const uint4*)(rb + 96);
    uint4 r4 = *(const uint4*)(rb + 128);
    uint4 r5 = *(const uint4*)(rb + 160);
    uint4 r6 = *(const uint4*)(rb + 192);
    uint4 r7 = *(const uint4*)(rb + 224);
    int i0 = *(const int*)(rb + 16);
    int i1 = *(const int*)(rb + 48);
    int i2 = *(const int*)(rb + 80);
    int i3 = *(const int*)(rb + 112);
    int i4 = *(const int*)(rb + 144);
    int i5 = *(const int*)(rb + 176);
    int i6 = *(const int*)(rb + 208);
    int i7 = *(const int*)(rb + 240);
    float hv0 = h[(size_t)i0 * 64 + lane];
    float hv1 = h[(size_t)i1 * 64 + lane];
    float hv2 = h[(size_t)i2 * 64 + lane];
    float hv3 = h[(size_t)i3 * 64 + lane];
    float hv4 = h[(size_t)i4 * 64 + lane];
    float hv5 = h[(size_t)i5 * 64 + lane];
    float hv6 = h[(size_t)i6 * 64 + lane];
    float hv7 = h[(size_t)i7 * 64 + lane];
    EDGE_STEP(hv0, r0)
    EDGE_STEP(hv1, r1)
    EDGE_STEP(hv2, r2)
    EDGE_STEP(hv3, r3)
    EDGE_STEP(hv4, r4)
    EDGE_STEP(hv5, r5)
    EDGE_STEP(hv6, r6)
    EDGE_STEP(hv7, r7)
  }
  for (; j + 4 <= s1; j += 4) {
    const char* rb = recs + (size_t)j * 32;
    uint4 r0 = *(const uint4*)(rb);
    uint4 r1 = *(const uint4*)(rb + 32);
    uint4 r2 = *(const uint4*)(rb + 64);
    uint4 r3 = *(const uint4*)(rb + 96);
    int i0 = *(const int*)(rb + 16);
    int i1 = *(const int*)(rb + 48);
    int i2 = *(const int*)(rb + 80);
    int i3 = *(const int*)(rb + 112);
    float hv0 = h[(size_t)i0 * 64 + lane];
    float hv1 = h[(size_t)i1 * 64 + lane];
    float hv2 = h[(size_t)i2 * 64 + lane];
    float hv3 = h[(size_t)i3 * 64 + lane];
    EDGE_STEP(hv0, r0)
    EDGE_STEP(hv1, r1)
    EDGE_STEP(hv2, r2)
    EDGE_STEP(hv3, r3)
  }
  for (; j < s1; ++j) {
    const char* rb = recs + (size_t)j * 32;
    uint4 r0 = *(const uint4*)(rb);
    int i0 = *(const int*)(rb + 16);
    float hv = h[(size_t)i0 * 64 + lane];
    EDGE_STEP(hv, r0)
  }
#undef EDGE_STEP
  out[(size_t)node * 64 + lane] = num / fmaxf(den, 1e-16f) + hd;
}

// Tiled-GEMM MLP: 256 threads, 64 nodes/block. Two-pass phase2 reuses the 64-row
// bufA for zT halves -> LDS 50.7KB -> 3 blocks/CU (12 waves) vs 2 before.
__global__ __launch_bounds__(256) void mlp_tile_kernel(
    const float* __restrict__ outv, const float* __restrict__ h_in,
    const float* __restrict__ W1, const float* __restrict__ b1,
    const float* __restrict__ lng, const float* __restrict__ lnb,
    const float* __restrict__ W2, const float* __restrict__ b2,
    float* __restrict__ h_out, float* __restrict__ nextsums, int n) {
  __shared__ float bufA[64 * 68];   // xT -> LN partials -> zT half -> out partials
  __shared__ float bufB[64 * 128];  // W1s then W2s
  __shared__ float mstat[128];      // mu[64], rstd[64]
  const int tid = threadIdx.x;
  const int tx = tid & 15, ty = tid >> 4;
  const int n0 = blockIdx.x * 64;
  // stage xT (transposed) + W1
#pragma unroll
  for (int i = 0; i < 16; ++i) {
    int gid = i * 256 + tid;
    int node = gid >> 6, c = gid & 63;
    int nd = n0 + node;
    bufA[c * 68 + node] = (nd < n) ? outv[(size_t)nd * 64 + c] : 0.f;
  }
  {
    const float4* w1g = (const float4*)W1;
    float4* w1s = (float4*)bufB;
#pragma unroll
    for (int i = 0; i < 8; ++i) w1s[i * 256 + tid] = w1g[i * 256 + tid];
  }
  __syncthreads();
  // ---- phase 1: y[4 nodes][8 ch] = x @ W1 + b1 ----
  const float4* b1v = (const float4*)b1;
  float4 acc0[4], acc1[4];
  {
    float4 bA = b1v[2 * ty], bB = b1v[2 * ty + 1];
#pragma unroll
    for (int i = 0; i < 4; ++i) { acc0[i] = bA; acc1[i] = bB; }
  }
  for (int k = 0; k < 64; ++k) {
    float4 xv = *(const float4*)&bufA[k * 68 + 4 * tx];
    float4 w0 = *(const float4*)&bufB[k * 128 + 8 * ty];
    float4 w1 = *(const float4*)&bufB[k * 128 + 8 * ty + 4];
#define FMA8(I, XS)                                                            \
    acc0[I].x = fmaf(XS, w0.x, acc0[I].x);                                     \
    acc0[I].y = fmaf(XS, w0.y, acc0[I].y);                                     \
    acc0[I].z = fmaf(XS, w0.z, acc0[I].z);                                     \
    acc0[I].w = fmaf(XS, w0.w, acc0[I].w);                                     \
    acc1[I].x = fmaf(XS, w1.x, acc1[I].x);                                     \
    acc1[I].y = fmaf(XS, w1.y, acc1[I].y);                                     \
    acc1[I].z = fmaf(XS, w1.z, acc1[I].z);                                     \
    acc1[I].w = fmaf(XS, w1.w, acc1[I].w);
    FMA8(0, xv.x) FMA8(1, xv.y) FMA8(2, xv.z) FMA8(3, xv.w)
#undef FMA8
  }
  __syncthreads();  // xT reads done; bufA becomes LN-partial scratch
  // LN partials per (node, ty) into bufA; stage W2 into bufB (W1 reads done)
  float* redS = bufA;
  float* redQ = bufA + 16 * 68;
#pragma unroll
  for (int i = 0; i < 4; ++i) {
    float si = ((acc0[i].x + acc0[i].y) + (acc0[i].z + acc0[i].w)) +
               ((acc1[i].x + acc1[i].y) + (acc1[i].z + acc1[i].w));
    float qi = 0.f;
    qi = fmaf(acc0[i].x, acc0[i].x, qi); qi = fmaf(acc0[i].y, acc0[i].y, qi);
    qi = fmaf(acc0[i].z, acc0[i].z, qi); qi = fmaf(acc0[i].w, acc0[i].w, qi);
    qi = fmaf(acc1[i].x, acc1[i].x, qi); qi = fmaf(acc1[i].y, acc1[i].y, qi);
    qi = fmaf(acc1[i].z, acc1[i].z, qi); qi = fmaf(acc1[i].w, acc1[i].w, qi);
    redS[ty * 68 + 4 * tx + i] = si;
    redQ[ty * 68 + 4 * tx + i] = qi;
  }
  {
    const float4* w2g = (const float4*)W2;
    float4* w2s = (float4*)bufB;
#pragma unroll
    for (int i = 0; i < 8; ++i) w2s[i * 256 + tid] = w2g[i * 256 + tid];
  }
  __syncthreads();
  if (tid < 64) {
    float S = 0.f, Q = 0.f;
#pragma unroll
    for (int t = 0; t < 16; ++t) { S += redS[t * 68 + tid]; Q += redQ[t * 68 + tid]; }
    float mu = S * (1.f / 128.f);
    float var = Q * (1.f / 128.f) - mu * mu;
    mstat[tid] = mu;
    mstat[64 + tid] = rsqrtf(var + 1e-5f);
  }
  __syncthreads();
  float mu0 = mstat[4 * tx + 0], mu1 = mstat[4 * tx + 1];
  float mu2 = mstat[4 * tx + 2], mu3 = mstat[4 * tx + 3];
  float r0 = mstat[64 + 4 * tx + 0], r1 = mstat[64 + 4 * tx + 1];
  float r2 = mstat[64 + 4 * tx + 2], r3 = mstat[64 + 4 * tx + 3];
  const float4* lgv = (const float4*)lng;
  const float4* lbv = (const float4*)lnb;
  float4 g0 = lgv[2 * ty], g1 = lgv[2 * ty + 1];
  float4 e0 = lbv[2 * ty], e1 = lbv[2 * ty + 1];
#define ZROW(ROWLOCAL, A, C, G, E)                                             \
  { float4 zr;                                                                 \
    zr.x = fmaxf((A[0].C - mu0) * r0 * (G).C + (E).C, 0.f);                    \
    zr.y = fmaxf((A[1].C - mu1) * r1 * (G).C + (E).C, 0.f);                    \
    zr.z = fmaxf((A[2].C - mu2) * r2 * (G).C + (E).C, 0.f);                    \
    zr.w = fmaxf((A[3].C - mu3) * r3 * (G).C + (E).C, 0.f);                    \
    *(float4*)&bufA[(ROWLOCAL) * 68 + 4 * tx] = zr; }
  // ---- phase 2a: z rows 0..63 (ty<8) staged, accumulate k=0..63 ----
  if (ty < 8) {
    ZROW(8 * ty + 0, acc0, x, g0, e0)
    ZROW(8 * ty + 1, acc0, y, g0, e0)
    ZROW(8 * ty + 2, acc0, z, g0, e0)
    ZROW(8 * ty + 3, acc0, w, g0, e0)
    ZROW(8 * ty + 4, acc1, x, g1, e1)
    ZROW(8 * ty + 5, acc1, y, g1, e1)
    ZROW(8 * ty + 6, acc1, z, g1, e1)
    ZROW(8 * ty + 7, acc1, w, g1, e1)
  }
  __syncthreads();
  float4 oa[4];
  {
    float4 bc = ((const float4*)b2)[ty];
#pragma unroll
    for (int i = 0; i < 4; ++i) oa[i] = bc;
  }
#define P2(I, ZS, WV)                                                          \
  oa[I].x = fmaf(ZS, WV.x, oa[I].x);                                           \
  oa[I].y = fmaf(ZS, WV.y, oa[I].y);                                           \
  oa[I].z = fmaf(ZS, WV.z, oa[I].z);                                           \
  oa[I].w = fmaf(ZS, WV.w, oa[I].w);
  for (int k = 0; k < 64; ++k) {
    float4 zv = *(const float4*)&bufA[k * 68 + 4 * tx];
    float4 wv = *(const float4*)&bufB[k * 64 + 4 * ty];
    P2(0, zv.x, wv) P2(1, zv.y, wv) P2(2, zv.z, wv) P2(3, zv.w, wv)
  }
  __syncthreads();
  // ---- phase 2b: z rows 64..127 (ty>=8) staged, accumulate k=64..127 ----
  if (ty >= 8) {
    int tyb = ty - 8;
    ZROW(8 * tyb + 0, acc0, x, g0, e0)
    ZROW(8 * tyb + 1, acc0, y, g0, e0)
    ZROW(8 * tyb + 2, acc0, z, g0, e0)
    ZROW(8 * tyb + 3, acc0, w, g0, e0)
    ZROW(8 * tyb + 4, acc1, x, g1, e1)
    ZROW(8 * tyb + 5, acc1, y, g1, e1)
    ZROW(8 * tyb + 6, acc1, z, g1, e1)
    ZROW(8 * tyb + 7, acc1, w, g1, e1)
  }
  __syncthreads();
  for (int k = 64; k < 128; ++k) {
    float4 zv = *(const float4*)&bufA[(k - 64) * 68 + 4 * tx];
    float4 wv = *(const float4*)&bufB[k * 64 + 4 * ty];
    P2(0, zv.x, wv) P2(1, zv.y, wv) P2(2, zv.z, wv) P2(3, zv.w, wv)
  }
#undef P2
#undef ZROW
  // residual + store + per-channel partials
  float4 ps = make_float4(0.f, 0.f, 0.f, 0.f);
  float4 pq = make_float4(0.f, 0.f, 0.f, 0.f);
#pragma unroll
  for (int i = 0; i < 4; ++i) {
    int nd = n0 + 4 * tx + i;
    if (nd < n) {
      float4 hv = *(const float4*)&h_in[(size_t)nd * 64 + 4 * ty];
      float4 v;
      v.x = hv.x + oa[i].x; v.y = hv.y + oa[i].y;
      v.z = hv.z + oa[i].z; v.w = hv.w + oa[i].w;
      *(float4*)&h_out[(size_t)nd * 64 + 4 * ty] = v;
      ps.x += v.x; ps.y += v.y; ps.z += v.z; ps.w += v.w;
      pq.x = fmaf(v.x, v.x, pq.x); pq.y = fmaf(v.y, v.y, pq.y);
      pq.z = fmaf(v.z, v.z, pq.z); pq.w = fmaf(v.w, v.w, pq.w);
    }
  }
  if (nextsums != nullptr) {
    __syncthreads();  // phase2b zT reads done; bufA free
    float* rs = bufA;             // [64 ch][17]
    float* rq = bufA + 64 * 17;
    rs[(4 * ty + 0) * 17 + tx] = ps.x;
    rs[(4 * ty + 1) * 17 + tx] = ps.y;
    rs[(4 * ty + 2) * 17 + tx] = ps.z;
    rs[(4 * ty + 3) * 17 + tx] = ps.w;
    rq[(4 * ty + 0) * 17 + tx] = pq.x;
    rq[(4 * ty + 1) * 17 + tx] = pq.y;
    rq[(4 * ty + 2) * 17 + tx] = pq.z;
    rq[(4 * ty + 3) * 17 + tx] = pq.w;
    __syncthreads();
    if (tid < 64) {
      float S = 0.f, Q = 0.f;
#pragma unroll
      for (int t = 0; t < 16; ++t) { S += rs[tid * 17 + t]; Q += rq[tid * 17 + t]; }
      int slot = blockIdx.x & 7;
      atomicAdd(&nextsums[slot * 128 + tid], S);
      atomicAdd(&nextsums[slot * 128 + 64 + tid], Q);
    }
  }
}

extern "C" void kernel_launch(void* const* d_in, const int* in_sizes, int n_in,
                              void* d_out, int out_size, void* d_ws, size_t ws_size,
                              hipStream_t stream) {
  const float* x = (const float*)d_in[0];
  const int* edge_index = (const int*)d_in[1];
  const float* edge_attr = (const float*)d_in[2];
  const float* node_W = (const float*)d_in[3];
  const float* node_b = (const float*)d_in[4];
  const float* edge_W = (const float*)d_in[5];
  const float* edge_b = (const float*)d_in[6];
  const float* bn_g = (const float*)d_in[7];
  const float* bn_b = (const float*)d_in[8];
  const float* t = (const float*)d_in[9];
  const float* W1 = (const float*)d_in[10];
  const float* b1 = (const float*)d_in[11];
  const float* ln_g = (const float*)d_in[12];
  const float* ln_b = (const float*)d_in[13];
  const float* W2 = (const float*)d_in[14];
  const float* b2 = (const float*)d_in[15];

  int N = in_sizes[0] / HDIM;
  int E = in_sizes[1] / 2;
  const int* srcp = edge_index;
  const int* dstp = edge_index + E;

  char* ws = (char*)d_ws;
  size_t off = 0;
  auto alloc = [&](size_t bytes) {
    char* p = ws + off;
    off = (off + bytes + 255) & ~(size_t)255;
    return p;
  };
  int* deg = (int*)alloc((size_t)N * 4);
  int* rowstart = (int*)alloc(((size_t)N + 1) * 4);
  int* idxw = (int*)alloc((size_t)E * 4);
  int* partials = (int*)alloc(1024 * 4);
  float* bnsums = (float*)alloc(3 * 1024 * 4);  // 3 layers x 8 slots x 128
  char* recs = (char*)alloc((size_t)E * 32);
  float* h = (float*)alloc((size_t)N * 64 * 4);
  float* outv = (float*)alloc((size_t)N * 64 * 4);
  (void)ws_size; (void)n_in; (void)out_size;

  int nb = (N + 255) / 256;
  hipMemsetAsync(bnsums, 0, 3 * 1024 * 4, stream);
  init_h_stats_kernel<<<512, 256, 0, stream>>>(x, node_W, node_b, h, bnsums, deg, N);
  deg_kernel<<<(E + 255) / 256, 256, 0, stream>>>(dstp, deg, idxw, E);
  scan_part_kernel<<<nb, 256, 0, stream>>>(deg, partials, N);
  scan_top_kernel<<<1, 1024, 0, stream>>>(partials, nb);
  scan_fill_kernel<<<nb, 256, 0, stream>>>(deg, partials, rowstart, N, E);
  fill_kernel<<<(E + 255) / 256, 256, 0, stream>>>(srcp, dstp, idxw, rowstart, edge_attr, recs, E);

  float invN = 1.0f / (float)N;
  int mlp_blocks = (N + 63) / 64;
  for (int l = 0; l < 3; ++l) {
    aggregate_kernel<<<(N + 3) / 4, 256, 0, stream>>>(
        h, bnsums + l * 1024, bn_g + l * 64, bn_b + l * 64, rowstart, recs,
        edge_W, edge_b, t + l, outv, N, invN);
    float* hout = (l == 2) ? (float*)d_out : h;
    float* nxt = (l == 2) ? nullptr : (bnsums + (l + 1) * 1024);
    mlp_tile_kernel<<<mlp_blocks, 256, 0, stream>>>(outv, h, W1 + (size_t)l * 8192, b1 + l * 128,
                                                    ln_g + l * 128, ln_b + l * 128,
                                                    W2 + (size_t)l * 8192, b2 + l * 64, hout, nxt, N);
  }
}